// Round 1
// baseline (4562.902 us; speedup 1.0000x reference)
//
#include <hip/hip_runtime.h>
#include <math.h>

#define DIM 1024
#define NQ 8192
#define NK 8192

// ---------------- small kernels: var -> MLP -> bias_weight ----------------

__global__ void var_partial_kernel(const float* __restrict__ k,
                                   float* __restrict__ ps, float* __restrict__ pq) {
  int col = blockIdx.x * 256 + threadIdx.x;      // 4 col-blocks x 256
  int r0  = blockIdx.y * 256;                    // 32 row-blocks
  float s = 0.f, q = 0.f;
  for (int r = 0; r < 256; ++r) {
    float x = k[(size_t)(r0 + r) * DIM + col];
    s += x; q += x * x;
  }
  ps[blockIdx.y * DIM + col] = s;
  pq[blockIdx.y * DIM + col] = q;
}

__global__ void gfv_kernel(const float* __restrict__ ps, const float* __restrict__ pq,
                           float* __restrict__ gfv) {
  int col = blockIdx.x * 256 + threadIdx.x;
  float s = 0.f, q = 0.f;
  for (int c = 0; c < 32; ++c) { s += ps[c * DIM + col]; q += pq[c * DIM + col]; }
  const float n = 8192.f;
  gfv[col] = (q - s * s / n) / (n - 1.f);        // torch.var unbiased (ddof=1)
}

__global__ void h1_partial_kernel(const float* __restrict__ gfv, const float* __restrict__ W1,
                                  float* __restrict__ h1p) {
  int j  = blockIdx.x * 256 + threadIdx.x;       // 8 blocks x 256 -> 2048 outputs
  int d0 = blockIdx.y * 128;                     // 8 d-chunks
  float acc = 0.f;
  for (int d = 0; d < 128; ++d)
    acc += gfv[d0 + d] * W1[(size_t)(d0 + d) * 2048 + j];
  h1p[blockIdx.y * 2048 + j] = acc;
}

__global__ void bw_kernel(const float* __restrict__ h1p, const float* __restrict__ b1,
                          const float* __restrict__ W2, const float* __restrict__ b2,
                          float* __restrict__ bw) {
  __shared__ float red[256];
  int t = threadIdx.x;
  float acc = 0.f;
  for (int i = 0; i < 8; ++i) {
    int j = i * 256 + t;
    float h = b1[j];
    for (int c = 0; c < 8; ++c) h += h1p[c * 2048 + j];
    h = fmaxf(h, 0.f);
    acc += h * W2[j];
  }
  red[t] = acc; __syncthreads();
  for (int s = 128; s > 0; s >>= 1) { if (t < s) red[t] += red[t + s]; __syncthreads(); }
  if (t == 0) bw[0] = 1.f / (1.f + __expf(-(red[0] + b2[0])));
}

__global__ void centers_kernel(const float4* __restrict__ qb, const float4* __restrict__ rb,
                               float2* __restrict__ cq, float2* __restrict__ cr) {
  int i = blockIdx.x * 256 + threadIdx.x;        // 32 blocks -> 8192
  float4 a = qb[i];
  cq[i] = make_float2(0.5f * (a.x + a.z), 0.5f * (a.y + a.w));
  float4 b = rb[i];
  cr[i] = make_float2(0.5f * (b.x + b.z), 0.5f * (b.y + b.w));
}

// ---------------- f32 register-blocked GEMM ----------------
// C[M][N] = alpha * A[M][K] @ (TRANSB ? B[N][K]^T : B[K][N]) (+ bias[N])
// 64x64 tile, BK=16, 256 threads, 4x4 per thread.

#define BM 64
#define BN 64
#define BK 16

template <bool TRANSB, bool BIAS>
__global__ __launch_bounds__(256) void gemm_kernel(
    const float* __restrict__ A, const float* __restrict__ B, float* __restrict__ C,
    const float* __restrict__ bias, int M, int N, int K, float alpha) {
  __shared__ float As[BK][BM + 4];   // +4 pad keeps 16B alignment, breaks bank stride
  __shared__ float Bs[BK][BN + 4];

  const int t  = threadIdx.x;
  const int tx = t % 16;             // N direction
  const int ty = t / 16;             // M direction
  const int row0 = blockIdx.y * BM;
  const int col0 = blockIdx.x * BN;

  // A loader: one float4 per thread: A[row0+arow][k0+acol .. +3]
  const int arow = t / 4;
  const int acol = (t % 4) * 4;
  // B loader
  const int brow = TRANSB ? (t / 4) : (t / 16);
  const int bcol = TRANSB ? ((t % 4) * 4) : ((t % 16) * 4);

  float acc[4][4] = {{0.f}};

  for (int k0 = 0; k0 < K; k0 += BK) {
    float4 av = *(const float4*)&A[(size_t)(row0 + arow) * K + k0 + acol];
    As[acol + 0][arow] = av.x;
    As[acol + 1][arow] = av.y;
    As[acol + 2][arow] = av.z;
    As[acol + 3][arow] = av.w;
    if (TRANSB) {
      float4 bv = *(const float4*)&B[(size_t)(col0 + brow) * K + k0 + bcol];
      Bs[bcol + 0][brow] = bv.x;
      Bs[bcol + 1][brow] = bv.y;
      Bs[bcol + 2][brow] = bv.z;
      Bs[bcol + 3][brow] = bv.w;
    } else {
      float4 bv = *(const float4*)&B[(size_t)(k0 + brow) * N + col0 + bcol];
      *(float4*)&Bs[brow][bcol] = bv;
    }
    __syncthreads();

#pragma unroll
    for (int kk = 0; kk < BK; ++kk) {
      float a[4], b[4];
      *(float4*)a = *(const float4*)&As[kk][ty * 4];
      *(float4*)b = *(const float4*)&Bs[kk][tx * 4];
#pragma unroll
      for (int i = 0; i < 4; ++i)
#pragma unroll
        for (int j = 0; j < 4; ++j) acc[i][j] += a[i] * b[j];
    }
    __syncthreads();
  }

#pragma unroll
  for (int i = 0; i < 4; ++i) {
    float o[4];
#pragma unroll
    for (int j = 0; j < 4; ++j) {
      o[j] = acc[i][j] * alpha;
      if (BIAS) o[j] += bias[col0 + tx * 4 + j];
    }
    *(float4*)&C[(size_t)(row0 + ty * 4 + i) * N + col0 + tx * 4] = *(float4*)o;
  }
}

// ---------------- fused bias + row softmax (in place on a stripe) ----------------

__global__ __launch_bounds__(256) void softmax_bias_kernel(
    float* __restrict__ S, const float2* __restrict__ cq, const float2* __restrict__ cr,
    const float* __restrict__ bwp, int qr0) {
  __shared__ float red[256];
  const int rs = blockIdx.x;
  const int t  = threadIdx.x;
  float* row = S + (size_t)rs * NK;
  const float2 cqv = cq[qr0 + rs];
  const float bw = bwp[0];

  float l[32];
  float mx = -1e30f;
#pragma unroll
  for (int i = 0; i < 8; ++i) {
    int j4 = i * 256 + t;
    float4 s4 = *(const float4*)&row[(size_t)j4 * 4];
    float vals[4] = {s4.x, s4.y, s4.z, s4.w};
#pragma unroll
    for (int u = 0; u < 4; ++u) {
      int j = j4 * 4 + u;
      float2 c = cr[j];
      float dx = cqv.x - c.x, dy = cqv.y - c.y;
      float lv = vals[u] - bw * sqrtf(dx * dx + dy * dy + 1e-8f);
      l[i * 4 + u] = lv;
      mx = fmaxf(mx, lv);
    }
  }
  red[t] = mx; __syncthreads();
  for (int s = 128; s > 0; s >>= 1) { if (t < s) red[t] = fmaxf(red[t], red[t + s]); __syncthreads(); }
  mx = red[0]; __syncthreads();

  float sum = 0.f;
#pragma unroll
  for (int i = 0; i < 32; ++i) { float e = __expf(l[i] - mx); l[i] = e; sum += e; }
  red[t] = sum; __syncthreads();
  for (int s = 128; s > 0; s >>= 1) { if (t < s) red[t] += red[t + s]; __syncthreads(); }
  float inv = 1.f / red[0];

#pragma unroll
  for (int i = 0; i < 8; ++i) {
    int j4 = i * 256 + t;
    float4 p4 = {l[i * 4] * inv, l[i * 4 + 1] * inv, l[i * 4 + 2] * inv, l[i * 4 + 3] * inv};
    *(float4*)&row[(size_t)j4 * 4] = p4;
  }
}

// ---------------- host ----------------

extern "C" void kernel_launch(void* const* d_in, const int* in_sizes, int n_in,
                              void* d_out, int out_size, void* d_ws, size_t ws_size,
                              hipStream_t stream) {
  const float* q  = (const float*)d_in[0];
  const float* k  = (const float*)d_in[1];
  const float* v  = (const float*)d_in[2];
  const float* rb = (const float*)d_in[3];
  const float* qb = (const float*)d_in[4];
  const float* Wq = (const float*)d_in[5];
  const float* Wk = (const float*)d_in[6];
  const float* Wv = (const float*)d_in[7];
  const float* Wp = (const float*)d_in[8];
  const float* bp = (const float*)d_in[9];
  const float* W1 = (const float*)d_in[10];
  const float* b1 = (const float*)d_in[11];
  const float* W2 = (const float*)d_in[12];
  const float* b2 = (const float*)d_in[13];
  float* out = (float*)d_out;
  float* ws  = (float*)d_ws;

  const size_t PROJ = (size_t)NQ * DIM;  // 8M floats
  float* qh  = ws;
  float* kh  = qh + PROJ;
  float* vh  = kh + PROJ;
  float* cq  = vh + PROJ;          // 2*8192
  float* cr  = cq + 2 * NQ;        // 2*8192
  float* ps  = cr + 2 * NK;        // 32*1024
  float* pq  = ps + 32 * DIM;      // 32*1024
  float* gfv = pq + 32 * DIM;      // 1024
  float* h1p = gfv + DIM;          // 8*2048
  float* bw  = h1p + 8 * 2048;     // 1 (+pad)
  float* Sbuf = bw + 16;
  size_t fixed_f = (size_t)(Sbuf - ws);

  size_t avail = (ws_size / 4 > fixed_f) ? (ws_size / 4 - fixed_f) : 0;
  int SR = 64;  // stripe of q-rows whose S fits in workspace
  for (int cand = 8192; cand >= 64; cand >>= 1) {
    if ((size_t)cand * (NK + DIM) <= avail) { SR = cand; break; }
  }
  float* Obuf = Sbuf + (size_t)SR * NK;

  // bias_weight = sigmoid(MLP(var(k, dim=0)))
  var_partial_kernel<<<dim3(4, 32), 256, 0, stream>>>(k, ps, pq);
  gfv_kernel<<<4, 256, 0, stream>>>(ps, pq, gfv);
  h1_partial_kernel<<<dim3(8, 8), 256, 0, stream>>>(gfv, W1, h1p);
  bw_kernel<<<1, 256, 0, stream>>>(h1p, b1, W2, b2, bw);
  centers_kernel<<<32, 256, 0, stream>>>((const float4*)qb, (const float4*)rb,
                                         (float2*)cq, (float2*)cr);

  // projections: qh = (q@Wq)*hd^-0.5, kh = k@Wk, vh = v@Wv
  gemm_kernel<false, false><<<dim3(DIM / BN, NQ / BM), 256, 0, stream>>>(
      q, Wq, qh, nullptr, NQ, DIM, DIM, 0.03125f);
  gemm_kernel<false, false><<<dim3(DIM / BN, NK / BM), 256, 0, stream>>>(
      k, Wk, kh, nullptr, NK, DIM, DIM, 1.f);
  gemm_kernel<false, false><<<dim3(DIM / BN, NK / BM), 256, 0, stream>>>(
      v, Wv, vh, nullptr, NK, DIM, DIM, 1.f);

  for (int s0 = 0; s0 < NQ; s0 += SR) {
    // S = qh_stripe @ kh^T
    gemm_kernel<true, false><<<dim3(NK / BN, SR / BM), 256, 0, stream>>>(
        qh + (size_t)s0 * DIM, kh, Sbuf, nullptr, SR, NK, DIM, 1.f);
    // S -> softmax(S - bw*dist) in place
    softmax_bias_kernel<<<SR, 256, 0, stream>>>(
        Sbuf, (const float2*)cq, (const float2*)cr, bw, s0);
    // O = P @ vh
    gemm_kernel<false, false><<<dim3(DIM / BN, SR / BM), 256, 0, stream>>>(
        Sbuf, vh, Obuf, nullptr, SR, DIM, NK, 1.f);
    // out_stripe = O @ Wp + bp
    gemm_kernel<false, true><<<dim3(DIM / BN, SR / BM), 256, 0, stream>>>(
        Obuf, Wp, out + (size_t)s0 * DIM, bp, SR, DIM, DIM, 1.f);
  }
}

// Round 2
// 693.615 us; speedup vs baseline: 6.5784x; 6.5784x over previous
//
#include <hip/hip_runtime.h>
#include <math.h>

#define DIM 1024
#define NQ 8192
#define NK 8192

typedef unsigned short u16;
typedef __attribute__((ext_vector_type(8))) short short8;
typedef __attribute__((ext_vector_type(8))) u16 u16x8;
typedef __attribute__((ext_vector_type(4))) u16 u16x4;
typedef __attribute__((ext_vector_type(4))) float f32x4;
typedef __attribute__((address_space(1))) const unsigned int gu32;
typedef __attribute__((address_space(3))) unsigned int lu32;

__device__ inline u16 f2bf(float f) {
  unsigned u = __builtin_bit_cast(unsigned, f);
  u += 0x7fff + ((u >> 16) & 1);
  return (u16)(u >> 16);
}
__device__ inline float bf2f(u16 h) {
  unsigned u = ((unsigned)h) << 16;
  return __builtin_bit_cast(float, u);
}

// ---------------- small kernels: var -> MLP -> bias_weight ----------------

__global__ void var_partial_kernel(const float* __restrict__ k,
                                   float* __restrict__ ps, float* __restrict__ pq) {
  int col = blockIdx.x * 256 + threadIdx.x;
  int r0  = blockIdx.y * 256;
  float s = 0.f, q = 0.f;
  for (int r = 0; r < 256; ++r) {
    float x = k[(size_t)(r0 + r) * DIM + col];
    s += x; q += x * x;
  }
  ps[blockIdx.y * DIM + col] = s;
  pq[blockIdx.y * DIM + col] = q;
}

__global__ void gfv_kernel(const float* __restrict__ ps, const float* __restrict__ pq,
                           float* __restrict__ gfv) {
  int col = blockIdx.x * 256 + threadIdx.x;
  float s = 0.f, q = 0.f;
  for (int c = 0; c < 32; ++c) { s += ps[c * DIM + col]; q += pq[c * DIM + col]; }
  const float n = 8192.f;
  gfv[col] = (q - s * s / n) / (n - 1.f);  // unbiased var (ddof=1)
}

__global__ void h1_partial_kernel(const float* __restrict__ gfv, const float* __restrict__ W1,
                                  float* __restrict__ h1p) {
  int j  = blockIdx.x * 256 + threadIdx.x;
  int d0 = blockIdx.y * 128;
  float acc = 0.f;
  for (int d = 0; d < 128; ++d)
    acc += gfv[d0 + d] * W1[(size_t)(d0 + d) * 2048 + j];
  h1p[blockIdx.y * 2048 + j] = acc;
}

__global__ void bw_kernel(const float* __restrict__ h1p, const float* __restrict__ b1,
                          const float* __restrict__ W2, const float* __restrict__ b2,
                          float* __restrict__ bw) {
  __shared__ float red[256];
  int t = threadIdx.x;
  float acc = 0.f;
  for (int i = 0; i < 8; ++i) {
    int j = i * 256 + t;
    float h = b1[j];
    for (int c = 0; c < 8; ++c) h += h1p[c * 2048 + j];
    h = fmaxf(h, 0.f);
    acc += h * W2[j];
  }
  red[t] = acc; __syncthreads();
  for (int s = 128; s > 0; s >>= 1) { if (t < s) red[t] += red[t + s]; __syncthreads(); }
  if (t == 0) bw[0] = 1.f / (1.f + __expf(-(red[0] + b2[0])));
}

__global__ void centers_kernel(const float4* __restrict__ qb, const float4* __restrict__ rb,
                               float2* __restrict__ cq, float2* __restrict__ cr) {
  int i = blockIdx.x * 256 + threadIdx.x;
  float4 a = qb[i];
  cq[i] = make_float2(0.5f * (a.x + a.z), 0.5f * (a.y + a.w));
  float4 b = rb[i];
  cr[i] = make_float2(0.5f * (b.x + b.z), 0.5f * (b.y + b.w));
}

// ---------------- conversion kernels ----------------

__global__ void f2bf_vec_kernel(const float4* __restrict__ in, u16x4* __restrict__ out, int n4) {
  for (int i = blockIdx.x * 256 + threadIdx.x; i < n4; i += gridDim.x * 256) {
    float4 v = in[i];
    u16x4 o;
    o[0] = f2bf(v.x); o[1] = f2bf(v.y); o[2] = f2bf(v.z); o[3] = f2bf(v.w);
    out[i] = o;
  }
}

// transpose-convert 1024x1024 f32 W -> bf16 WT[n][k] = W[k][n]
__global__ __launch_bounds__(256) void wtrans_kernel(const float* __restrict__ W, u16* __restrict__ WT) {
  __shared__ float tile[64][65];
  const int t = threadIdx.x;
  const int kb = blockIdx.x * 64, nb = blockIdx.y * 64;
#pragma unroll
  for (int i = 0; i < 16; ++i) {
    int r = i * 4 + (t >> 6), c = t & 63;            // r: k-dir, c: n-dir
    tile[c][r] = W[(size_t)(kb + r) * 1024 + nb + c];
  }
  __syncthreads();
#pragma unroll
  for (int i = 0; i < 16; ++i) {
    int n = i * 4 + (t >> 6), kk = t & 63;
    WT[(size_t)(nb + n) * 1024 + kb + kk] = f2bf(tile[n][kk]);
  }
}

// ---------------- bf16 MFMA GEMM: C[M][N] = alpha*A[M][K] @ Bt[N][K]^T ----------------
// 128x128 tile, BK=32, 256 threads = 4 waves (2x2), 4x4 16x16x32 frags per wave.
// OUT: 0 = f32 + bias, 1 = bf16, 2 = bf16 transposed (C[N][M], ldc = M)

#define TM 128
#define TN 128
#define TK 32

template <int OUT>
__global__ __launch_bounds__(256) void bgemm_kernel(
    const u16* __restrict__ A, const u16* __restrict__ Bt, void* __restrict__ C,
    const float* __restrict__ bias, int M, int N, int K, int ldc, float alpha) {
  __shared__ __align__(16) u16 As[TM * TK];
  __shared__ __align__(16) u16 Bs[TN * TK];

  const int t = threadIdx.x;
  const int l = t & 63;
  const int w = t >> 6;
  const int wm = w >> 1, wn = w & 1;
  const size_t row0 = (size_t)blockIdx.y * TM;
  const size_t col0 = (size_t)blockIdx.x * TN;

  f32x4 acc[4][4];
#pragma unroll
  for (int m = 0; m < 4; ++m)
#pragma unroll
    for (int n = 0; n < 4; ++n) acc[m][n] = (f32x4){0.f, 0.f, 0.f, 0.f};

  const int lane_r = l & 15;
  const int kgrp = (l >> 4) * 8;

  for (int k0 = 0; k0 < K; k0 += TK) {
    // stage 128x32 bf16 A and B tiles via async global->LDS, 16B per lane
#pragma unroll
    for (int j = 0; j < 2; ++j) {
      int idx = j * 256 + t;                 // 0..511
      int r = idx >> 2, c8 = (idx & 3) << 3;
      __builtin_amdgcn_global_load_lds((gu32*)(A + (row0 + r) * K + k0 + c8),
                                       (lu32*)(As + idx * 8), 16, 0, 0);
      __builtin_amdgcn_global_load_lds((gu32*)(Bt + (col0 + r) * K + k0 + c8),
                                       (lu32*)(Bs + idx * 8), 16, 0, 0);
    }
    __syncthreads();

    short8 a[4], b[4];
#pragma unroll
    for (int m = 0; m < 4; ++m)
      a[m] = *(const short8*)&As[(wm * 64 + m * 16 + lane_r) * TK + kgrp];
#pragma unroll
    for (int n = 0; n < 4; ++n)
      b[n] = *(const short8*)&Bs[(wn * 64 + n * 16 + lane_r) * TK + kgrp];
#pragma unroll
    for (int m = 0; m < 4; ++m)
#pragma unroll
      for (int n = 0; n < 4; ++n)
        acc[m][n] = __builtin_amdgcn_mfma_f32_16x16x32_bf16(a[m], b[n], acc[m][n], 0, 0, 0);
    __syncthreads();
  }

  // epilogue: D col = lane&15, row = (lane>>4)*4 + reg  [m89 verified layout]
#pragma unroll
  for (int m = 0; m < 4; ++m) {
#pragma unroll
    for (int n = 0; n < 4; ++n) {
      size_t col = col0 + wn * 64 + n * 16 + lane_r;
      size_t rbase = row0 + wm * 64 + m * 16 + (l >> 4) * 4;
      if (OUT == 0) {
        float bv = bias[col];
#pragma unroll
        for (int j = 0; j < 4; ++j)
          ((float*)C)[(rbase + j) * (size_t)ldc + col] = acc[m][n][j] * alpha + bv;
      } else if (OUT == 1) {
#pragma unroll
        for (int j = 0; j < 4; ++j)
          ((u16*)C)[(rbase + j) * (size_t)ldc + col] = f2bf(acc[m][n][j] * alpha);
      } else {
        u16x4 p;
#pragma unroll
        for (int j = 0; j < 4; ++j) p[j] = f2bf(acc[m][n][j] * alpha);
        *(u16x4*)&((u16*)C)[col * (size_t)ldc + rbase] = p;
      }
    }
  }
}

// ---------------- fused bias + row softmax, bf16 in place ----------------

__global__ __launch_bounds__(256) void softmax_bias_bf16_kernel(
    u16* __restrict__ S, const float2* __restrict__ cq, const float2* __restrict__ cr,
    const float* __restrict__ bwp, int qr0) {
  __shared__ float red[256];
  const int t = threadIdx.x;
  u16* row = S + (size_t)blockIdx.x * NK;
  const float2 cqv = cq[qr0 + blockIdx.x];
  const float bw = bwp[0];

  float l[32];
  float mx = -1e30f;
#pragma unroll
  for (int i = 0; i < 4; ++i) {
    int base = (i * 256 + t) * 8;
    u16x8 u = *(const u16x8*)&row[base];
#pragma unroll
    for (int j = 0; j < 8; ++j) {
      float x = bf2f(u[j]);
      float2 c = cr[base + j];
      float dx = cqv.x - c.x, dy = cqv.y - c.y;
      float lv = x - bw * sqrtf(dx * dx + dy * dy + 1e-8f);
      l[i * 8 + j] = lv;
      mx = fmaxf(mx, lv);
    }
  }
  red[t] = mx; __syncthreads();
  for (int s = 128; s > 0; s >>= 1) { if (t < s) red[t] = fmaxf(red[t], red[t + s]); __syncthreads(); }
  mx = red[0]; __syncthreads();

  float sum = 0.f;
#pragma unroll
  for (int i = 0; i < 32; ++i) { float e = __expf(l[i] - mx); l[i] = e; sum += e; }
  red[t] = sum; __syncthreads();
  for (int s = 128; s > 0; s >>= 1) { if (t < s) red[t] += red[t + s]; __syncthreads(); }
  float inv = 1.f / red[0];

#pragma unroll
  for (int i = 0; i < 4; ++i) {
    int base = (i * 256 + t) * 8;
    u16x8 o;
#pragma unroll
    for (int j = 0; j < 8; ++j) o[j] = f2bf(l[i * 8 + j] * inv);
    *(u16x8*)&row[base] = o;
  }
}

// ---------------- host ----------------

extern "C" void kernel_launch(void* const* d_in, const int* in_sizes, int n_in,
                              void* d_out, int out_size, void* d_ws, size_t ws_size,
                              hipStream_t stream) {
  const float* q  = (const float*)d_in[0];
  const float* k  = (const float*)d_in[1];
  const float* v  = (const float*)d_in[2];
  const float* rb = (const float*)d_in[3];
  const float* qb = (const float*)d_in[4];
  const float* Wq = (const float*)d_in[5];
  const float* Wk = (const float*)d_in[6];
  const float* Wv = (const float*)d_in[7];
  const float* Wp = (const float*)d_in[8];
  const float* bp = (const float*)d_in[9];
  const float* W1 = (const float*)d_in[10];
  const float* b1 = (const float*)d_in[11];
  const float* W2 = (const float*)d_in[12];
  const float* b2 = (const float*)d_in[13];
  float* out = (float*)d_out;

  char* p = (char*)d_ws;
  const size_t PROJB = (size_t)NQ * DIM * sizeof(u16);     // 16 MB
  u16* qbf = (u16*)p;            p += PROJB;
  u16* kbf = (u16*)p;            p += PROJB;
  u16* vbf = (u16*)p;            p += PROJB;
  u16* WqT = (u16*)p;            p += (size_t)DIM * DIM * 2;
  u16* WkT = (u16*)p;            p += (size_t)DIM * DIM * 2;
  u16* WvT = (u16*)p;            p += (size_t)DIM * DIM * 2;
  u16* WpT = (u16*)p;            p += (size_t)DIM * DIM * 2;
  u16* qh  = (u16*)p;            p += PROJB;
  u16* kh  = (u16*)p;            p += PROJB;
  u16* vhT = (u16*)p;            p += PROJB;
  float* cq  = (float*)p;        p += 2 * NQ * 4;
  float* cr  = (float*)p;        p += 2 * NK * 4;
  float* ps  = (float*)p;        p += 32 * DIM * 4;
  float* pq  = (float*)p;        p += 32 * DIM * 4;
  float* gfv = (float*)p;        p += DIM * 4;
  float* h1p = (float*)p;        p += 8 * 2048 * 4;
  float* bw  = (float*)p;        p += 64;
  size_t fixed_b = (size_t)(p - (char*)d_ws);

  int SR = 256;
  for (int cand = 8192; cand >= 256; cand >>= 1) {
    if (fixed_b + (size_t)cand * (NK + DIM) * 2 <= ws_size) { SR = cand; break; }
  }
  u16* Sbuf = (u16*)p;
  u16* Obuf = Sbuf + (size_t)SR * NK;

  // bias_weight = sigmoid(MLP(var(k, dim=0)))  [f32, tiny]
  var_partial_kernel<<<dim3(4, 32), 256, 0, stream>>>(k, ps, pq);
  gfv_kernel<<<4, 256, 0, stream>>>(ps, pq, gfv);
  h1_partial_kernel<<<dim3(8, 8), 256, 0, stream>>>(gfv, W1, h1p);
  bw_kernel<<<1, 256, 0, stream>>>(h1p, b1, W2, b2, bw);
  centers_kernel<<<32, 256, 0, stream>>>((const float4*)qb, (const float4*)rb,
                                         (float2*)cq, (float2*)cr);

  // convert inputs + weights to bf16 (weights transposed to [N][K])
  const int N4 = NQ * DIM / 4;
  f2bf_vec_kernel<<<2048, 256, 0, stream>>>((const float4*)q, (u16x4*)qbf, N4);
  f2bf_vec_kernel<<<2048, 256, 0, stream>>>((const float4*)k, (u16x4*)kbf, N4);
  f2bf_vec_kernel<<<2048, 256, 0, stream>>>((const float4*)v, (u16x4*)vbf, N4);
  wtrans_kernel<<<dim3(16, 16), 256, 0, stream>>>(Wq, WqT);
  wtrans_kernel<<<dim3(16, 16), 256, 0, stream>>>(Wk, WkT);
  wtrans_kernel<<<dim3(16, 16), 256, 0, stream>>>(Wv, WvT);
  wtrans_kernel<<<dim3(16, 16), 256, 0, stream>>>(Wp, WpT);

  // projections (MFMA): qh = (q@Wq)*hd^-0.5, kh = k@Wk, vhT = (v@Wv)^T
  bgemm_kernel<1><<<dim3(DIM / TN, NQ / TM), 256, 0, stream>>>(
      qbf, WqT, qh, nullptr, NQ, DIM, DIM, DIM, 0.03125f);
  bgemm_kernel<1><<<dim3(DIM / TN, NK / TM), 256, 0, stream>>>(
      kbf, WkT, kh, nullptr, NK, DIM, DIM, DIM, 1.f);
  bgemm_kernel<2><<<dim3(DIM / TN, NK / TM), 256, 0, stream>>>(
      vbf, WvT, vhT, nullptr, NK, DIM, DIM, NK, 1.f);

  for (int s0 = 0; s0 < NQ; s0 += SR) {
    // S = qh_stripe @ kh^T   (bf16 out)
    bgemm_kernel<1><<<dim3(NK / TN, SR / TM), 256, 0, stream>>>(
        qh + (size_t)s0 * DIM, kh, Sbuf, nullptr, SR, NK, DIM, NK, 1.f);
    // softmax(S - bw*dist) in place
    softmax_bias_bf16_kernel<<<SR, 256, 0, stream>>>(
        Sbuf, (const float2*)cq, (const float2*)cr, bw, s0);
    // O = P @ vh   (Bt = vhT)
    bgemm_kernel<1><<<dim3(DIM / TN, SR / TM), 256, 0, stream>>>(
        Sbuf, vhT, Obuf, nullptr, SR, DIM, NK, DIM, 1.f);
    // out_stripe = O @ Wp + bp   (f32 out)
    bgemm_kernel<0><<<dim3(DIM / TN, SR / TM), 256, 0, stream>>>(
        Obuf, WpT, out + (size_t)s0 * DIM, bp, SR, DIM, DIM, DIM, 1.f);
  }
}

// Round 3
// 652.285 us; speedup vs baseline: 6.9953x; 1.0634x over previous
//
#include <hip/hip_runtime.h>
#include <math.h>

#define DIM 1024
#define NQ 8192
#define NK 8192

typedef unsigned short u16;
typedef __attribute__((ext_vector_type(8))) short short8;
typedef __attribute__((ext_vector_type(8))) u16 u16x8;
typedef __attribute__((ext_vector_type(4))) u16 u16x4;
typedef __attribute__((ext_vector_type(4))) float f32x4;
typedef __attribute__((address_space(1))) const unsigned int gu32;
typedef __attribute__((address_space(3))) unsigned int lu32;

__device__ inline u16 f2bf(float f) {
  unsigned u = __builtin_bit_cast(unsigned, f);
  u += 0x7fff + ((u >> 16) & 1);
  return (u16)(u >> 16);
}
__device__ inline float bf2f(u16 h) {
  unsigned u = ((unsigned)h) << 16;
  return __builtin_bit_cast(float, u);
}

// ---------------- small kernels: var -> MLP -> bias_weight ----------------

__global__ void var_partial_kernel(const float* __restrict__ k,
                                   float* __restrict__ ps, float* __restrict__ pq) {
  int col = blockIdx.x * 256 + threadIdx.x;
  int r0  = blockIdx.y * 256;
  float s = 0.f, q = 0.f;
  for (int r = 0; r < 256; ++r) {
    float x = k[(size_t)(r0 + r) * DIM + col];
    s += x; q += x * x;
  }
  ps[blockIdx.y * DIM + col] = s;
  pq[blockIdx.y * DIM + col] = q;
}

__global__ void gfv_kernel(const float* __restrict__ ps, const float* __restrict__ pq,
                           float* __restrict__ gfv) {
  int col = blockIdx.x * 256 + threadIdx.x;
  float s = 0.f, q = 0.f;
  for (int c = 0; c < 32; ++c) { s += ps[c * DIM + col]; q += pq[c * DIM + col]; }
  const float n = 8192.f;
  gfv[col] = (q - s * s / n) / (n - 1.f);  // unbiased var (ddof=1)
}

__global__ void h1_partial_kernel(const float* __restrict__ gfv, const float* __restrict__ W1,
                                  float* __restrict__ h1p) {
  int j  = blockIdx.x * 256 + threadIdx.x;
  int d0 = blockIdx.y * 128;
  float acc = 0.f;
  for (int d = 0; d < 128; ++d)
    acc += gfv[d0 + d] * W1[(size_t)(d0 + d) * 2048 + j];
  h1p[blockIdx.y * 2048 + j] = acc;
}

__global__ void bw_kernel(const float* __restrict__ h1p, const float* __restrict__ b1,
                          const float* __restrict__ W2, const float* __restrict__ b2,
                          float* __restrict__ bw) {
  __shared__ float red[256];
  int t = threadIdx.x;
  float acc = 0.f;
  for (int i = 0; i < 8; ++i) {
    int j = i * 256 + t;
    float h = b1[j];
    for (int c = 0; c < 8; ++c) h += h1p[c * 2048 + j];
    h = fmaxf(h, 0.f);
    acc += h * W2[j];
  }
  red[t] = acc; __syncthreads();
  for (int s = 128; s > 0; s >>= 1) { if (t < s) red[t] += red[t + s]; __syncthreads(); }
  if (t == 0) bw[0] = 1.f / (1.f + __expf(-(red[0] + b2[0])));
}

__global__ void centers_kernel(const float4* __restrict__ qb, const float4* __restrict__ rb,
                               float2* __restrict__ cq, float2* __restrict__ cr) {
  int i = blockIdx.x * 256 + threadIdx.x;
  float4 a = qb[i];
  cq[i] = make_float2(0.5f * (a.x + a.z), 0.5f * (a.y + a.w));
  float4 b = rb[i];
  cr[i] = make_float2(0.5f * (b.x + b.z), 0.5f * (b.y + b.w));
}

// ---------------- conversion kernels ----------------

__global__ void f2bf_vec_kernel(const float4* __restrict__ in, u16x4* __restrict__ out, int n4) {
  for (int i = blockIdx.x * 256 + threadIdx.x; i < n4; i += gridDim.x * 256) {
    float4 v = in[i];
    u16x4 o;
    o[0] = f2bf(v.x); o[1] = f2bf(v.y); o[2] = f2bf(v.z); o[3] = f2bf(v.w);
    out[i] = o;
  }
}

// transpose-convert 1024x1024 f32 W -> bf16 WT[n][k] = W[k][n]
__global__ __launch_bounds__(256) void wtrans_kernel(const float* __restrict__ W, u16* __restrict__ WT) {
  __shared__ float tile[64][65];
  const int t = threadIdx.x;
  const int kb = blockIdx.x * 64, nb = blockIdx.y * 64;
#pragma unroll
  for (int i = 0; i < 16; ++i) {
    int r = i * 4 + (t >> 6), c = t & 63;
    tile[c][r] = W[(size_t)(kb + r) * 1024 + nb + c];
  }
  __syncthreads();
#pragma unroll
  for (int i = 0; i < 16; ++i) {
    int n = i * 4 + (t >> 6), kk = t & 63;
    WT[(size_t)(nb + n) * 1024 + kb + kk] = f2bf(tile[n][kk]);
  }
}

// ---------------- 128x128 bf16 MFMA GEMM (round-2 proven; projections) ----------------
// C[M][N] = alpha*A[M][K] @ Bt[N][K]^T ; OUT: 0=f32+bias, 1=bf16, 2=bf16 transposed

#define TM 128
#define TN 128
#define TK 32

template <int OUT>
__global__ __launch_bounds__(256) void bgemm_kernel(
    const u16* __restrict__ A, const u16* __restrict__ Bt, void* __restrict__ C,
    const float* __restrict__ bias, int M, int N, int K, int ldc, float alpha) {
  __shared__ __align__(16) u16 As[TM * TK];
  __shared__ __align__(16) u16 Bs[TN * TK];

  const int t = threadIdx.x;
  const int l = t & 63;
  const int w = t >> 6;
  const int wm = w >> 1, wn = w & 1;
  const size_t row0 = (size_t)blockIdx.y * TM;
  const size_t col0 = (size_t)blockIdx.x * TN;

  f32x4 acc[4][4];
#pragma unroll
  for (int m = 0; m < 4; ++m)
#pragma unroll
    for (int n = 0; n < 4; ++n) acc[m][n] = (f32x4){0.f, 0.f, 0.f, 0.f};

  const int lane_r = l & 15;
  const int kgrp = (l >> 4) * 8;

  for (int k0 = 0; k0 < K; k0 += TK) {
#pragma unroll
    for (int j = 0; j < 2; ++j) {
      int idx = j * 256 + t;
      int r = idx >> 2, c8 = (idx & 3) << 3;
      __builtin_amdgcn_global_load_lds((gu32*)(A + (row0 + r) * K + k0 + c8),
                                       (lu32*)(As + idx * 8), 16, 0, 0);
      __builtin_amdgcn_global_load_lds((gu32*)(Bt + (col0 + r) * K + k0 + c8),
                                       (lu32*)(Bs + idx * 8), 16, 0, 0);
    }
    __syncthreads();

    short8 a[4], b[4];
#pragma unroll
    for (int m = 0; m < 4; ++m)
      a[m] = *(const short8*)&As[(wm * 64 + m * 16 + lane_r) * TK + kgrp];
#pragma unroll
    for (int n = 0; n < 4; ++n)
      b[n] = *(const short8*)&Bs[(wn * 64 + n * 16 + lane_r) * TK + kgrp];
#pragma unroll
    for (int m = 0; m < 4; ++m)
#pragma unroll
      for (int n = 0; n < 4; ++n)
        acc[m][n] = __builtin_amdgcn_mfma_f32_16x16x32_bf16(a[m], b[n], acc[m][n], 0, 0, 0);
    __syncthreads();
  }

#pragma unroll
  for (int m = 0; m < 4; ++m) {
#pragma unroll
    for (int n = 0; n < 4; ++n) {
      size_t col = col0 + wn * 64 + n * 16 + lane_r;
      size_t rbase = row0 + wm * 64 + m * 16 + (l >> 4) * 4;
      if (OUT == 0) {
        float bv = bias[col];
#pragma unroll
        for (int j = 0; j < 4; ++j)
          ((float*)C)[(rbase + j) * (size_t)ldc + col] = acc[m][n][j] * alpha + bv;
      } else if (OUT == 1) {
#pragma unroll
        for (int j = 0; j < 4; ++j)
          ((u16*)C)[(rbase + j) * (size_t)ldc + col] = f2bf(acc[m][n][j] * alpha);
      } else {
        u16x4 p;
#pragma unroll
        for (int j = 0; j < 4; ++j) p[j] = f2bf(acc[m][n][j] * alpha);
        *(u16x4*)&((u16*)C)[col * (size_t)ldc + rbase] = p;
      }
    }
  }
}

// ---------------- 256x256 8-phase bf16 MFMA GEMM (T1+T2+T3/T4+T5) ----------------
// C = alpha * A[M][K] @ Bt[N][K]^T. 512 threads = 8 waves (2M x 4N), BK=64,
// LDS 128 KiB: A[2buf][256][64] + B[2buf][256 perm][64], XOR-swizzled rows.
// B row permutation: row' = nq*128 + wn*32 + j  (nq = 32-col-block parity per wave)
// Staging: 8-KB units (64 rows), 2 global_load_lds/phase, uniform vmcnt(8)/phase.
// OUT: 0 = bf16 store (ldc elems), 1 = f32 store + blockIdx.y*cstride (split-K partial)

template <int VM>
__device__ __forceinline__ void waitvm() {
  if constexpr (VM == 8) asm volatile("s_waitcnt vmcnt(8)" ::: "memory");
  else if constexpr (VM == 4) asm volatile("s_waitcnt vmcnt(4)" ::: "memory");
  else asm volatile("s_waitcnt vmcnt(0)" ::: "memory");
}

#define STAGE_A(UNIT, KT, BUF)                                                      \
  __builtin_amdgcn_global_load_lds(                                                 \
      (gu32*)(Agp + (size_t)((UNIT) * 64) * ldaB + (size_t)(KT) * 128),             \
      (lu32*)(smem + (BUF) * 16384 + (UNIT) * 4096 + tid * 8), 16, 0, 0)

#define STAGE_B(UNIT, KT, BUF)                                                      \
  do {                                                                              \
    int _rp = (UNIT) * 64 + rr;                                                     \
    size_t _row = (size_t)(bn0 + ((_rp >> 5) & 3) * 64 + (_rp >> 7) * 32 + (_rp & 31)); \
    __builtin_amdgcn_global_load_lds(                                               \
        (gu32*)(Bgp + _row * ldbB + (size_t)(KT) * 128),                            \
        (lu32*)(smem + 32768 + (BUF) * 16384 + (UNIT) * 4096 + tid * 8), 16, 0, 0); \
  } while (0)

#define PHASE(BUF, MQ, NQ, VM, STAGES)                                              \
  do {                                                                              \
    short8 af[4][2], bfr[2][2];                                                     \
    _Pragma("unroll") for (int fr = 0; fr < 4; ++fr) {                              \
      af[fr][0] = *(const short8*)(smemc + (BUF) * 32768 + aRd + (MQ) * 8192 + fr * 2048 + koff0); \
      af[fr][1] = *(const short8*)(smemc + (BUF) * 32768 + aRd + (MQ) * 8192 + fr * 2048 + koff1); \
    }                                                                               \
    _Pragma("unroll") for (int fc = 0; fc < 2; ++fc) {                              \
      bfr[fc][0] = *(const short8*)(smemc + 65536 + (BUF) * 32768 + bRd + (NQ) * 16384 + fc * 2048 + koff0); \
      bfr[fc][1] = *(const short8*)(smemc + 65536 + (BUF) * 32768 + bRd + (NQ) * 16384 + fc * 2048 + koff1); \
    }                                                                               \
    STAGES;                                                                         \
    asm volatile("" ::: "memory");                                                  \
    __builtin_amdgcn_s_barrier();                                                   \
    asm volatile("" ::: "memory");                                                  \
    __builtin_amdgcn_s_setprio(1);                                                  \
    _Pragma("unroll") for (int fr = 0; fr < 4; ++fr)                                \
    _Pragma("unroll") for (int fc = 0; fc < 2; ++fc) {                              \
      acc[(MQ) * 4 + fr][(NQ) * 2 + fc] = __builtin_amdgcn_mfma_f32_16x16x32_bf16(  \
          af[fr][0], bfr[fc][0], acc[(MQ) * 4 + fr][(NQ) * 2 + fc], 0, 0, 0);       \
      acc[(MQ) * 4 + fr][(NQ) * 2 + fc] = __builtin_amdgcn_mfma_f32_16x16x32_bf16(  \
          af[fr][1], bfr[fc][1], acc[(MQ) * 4 + fr][(NQ) * 2 + fc], 0, 0, 0);       \
    }                                                                               \
    __builtin_amdgcn_s_setprio(0);                                                  \
    waitvm<VM>();                                                                   \
    asm volatile("" ::: "memory");                                                  \
    __builtin_amdgcn_s_barrier();                                                   \
    asm volatile("" ::: "memory");                                                  \
  } while (0)

#define ITER(T, LAST)                                                               \
  do {                                                                              \
    PHASE(0, 0, 0, 8, { STAGE_A(1, (T) + 1, 1); STAGE_A(3, (T) + 1, 1); });         \
    PHASE(0, 1, 0, 8, { STAGE_B(2, (T) + 1, 1); STAGE_B(3, (T) + 1, 1); });         \
    if (!(LAST)) {                                                                  \
      PHASE(0, 0, 1, 8, { STAGE_B(0, (T) + 2, 0); STAGE_B(1, (T) + 2, 0); });       \
      PHASE(0, 1, 1, 8, { STAGE_A(0, (T) + 2, 0); STAGE_A(2, (T) + 2, 0); });       \
      PHASE(1, 0, 0, 8, { STAGE_A(1, (T) + 2, 0); STAGE_A(3, (T) + 2, 0); });       \
      PHASE(1, 1, 0, 8, { STAGE_B(2, (T) + 2, 0); STAGE_B(3, (T) + 2, 0); });       \
      PHASE(1, 0, 1, 8, { STAGE_B(0, (T) + 3, 1); STAGE_B(1, (T) + 3, 1); });       \
      PHASE(1, 1, 1, 8, { STAGE_A(0, (T) + 3, 1); STAGE_A(2, (T) + 3, 1); });       \
    } else {                                                                        \
      PHASE(0, 0, 1, 8, {});                                                        \
      PHASE(0, 1, 1, 4, {});                                                        \
      PHASE(1, 0, 0, 0, {});                                                        \
      PHASE(1, 1, 0, 0, {});                                                        \
      PHASE(1, 0, 1, 0, {});                                                        \
      PHASE(1, 1, 1, 0, {});                                                        \
    }                                                                               \
  } while (0)

template <int OUT>
__global__ __launch_bounds__(512, 2) void gemm256_kernel(
    const u16* __restrict__ A, const u16* __restrict__ Bt, void* __restrict__ C,
    int NT, int nTn, size_t ldaB, size_t ldbB, int ldc, size_t kspanB,
    size_t cstride, float alpha) {
  __shared__ __align__(16) u16 smem[65536];  // 128 KiB
  const char* smemc = (const char*)smem;

  const int tid = threadIdx.x;
  const int l = tid & 63;
  const int wid = tid >> 6;
  const int wm = wid >> 2, wn = wid & 3;
  const int lane_r = l & 15;
  const int kq = l >> 4;
  const int rr = tid >> 3;

  // bijective XCD-chunked swizzle (gridDim.x % 8 == 0 guaranteed by host)
  const int nwg = gridDim.x;
  const int bid = blockIdx.x;
  const int swz = (bid & 7) * (nwg >> 3) + (bid >> 3);
  const int tm = swz / nTn, tn = swz % nTn;
  const int am0 = tm * 256, bn0 = tn * 256;

  const size_t kglob = kspanB * blockIdx.y;

  // swizzled k-offsets for ds_read (XOR with (row&7)<<4 == (lane_r&7)<<4)
  const int kx = (lane_r & 7) << 4;
  const int koff0 = ((kq << 4)) ^ kx;
  const int koff1 = (64 | (kq << 4)) ^ kx;
  const int aRd = (wm * 128 + lane_r) * 128;  // byte
  const int bRd = (wn * 32 + lane_r) * 128;   // byte

  // pre-swizzled global source base (inverse swizzle: col ^= (row&7)<<4)
  const int scol = ((tid & 7) ^ ((tid >> 3) & 7)) << 4;
  const char* Agp = (const char*)A + (size_t)(am0 + rr) * ldaB + kglob + scol;
  const char* Bgp = (const char*)Bt + kglob + scol;

  f32x4 acc[8][4];
#pragma unroll
  for (int i = 0; i < 8; ++i)
#pragma unroll
    for (int j = 0; j < 4; ++j) acc[i][j] = (f32x4){0.f, 0.f, 0.f, 0.f};

  // prologue: tile0 complete into buf0; B{0,1}(t1), A{0,2}(t1) into buf1
  STAGE_A(0, 0, 0); STAGE_A(1, 0, 0); STAGE_A(2, 0, 0); STAGE_A(3, 0, 0);
  STAGE_B(0, 0, 0); STAGE_B(1, 0, 0); STAGE_B(2, 0, 0); STAGE_B(3, 0, 0);
  STAGE_B(0, 1, 1); STAGE_B(1, 1, 1);
  STAGE_A(0, 1, 1); STAGE_A(2, 1, 1);
  waitvm<4>();
  asm volatile("" ::: "memory");
  __builtin_amdgcn_s_barrier();
  asm volatile("" ::: "memory");

  int t = 0;
  for (; t + 2 < NT; t += 2) ITER(t, false);
  ITER(t, true);

  // epilogue: C[row][col], 16x16x32 layout: col = lane&15, row = kq*4 + j
#pragma unroll
  for (int fp = 0; fp < 8; ++fp) {
#pragma unroll
    for (int fc = 0; fc < 4; ++fc) {
      int row = am0 + wm * 128 + fp * 16 + kq * 4;
      int col = bn0 + wn * 64 + fc * 16 + lane_r;
      if (OUT == 0) {
#pragma unroll
        for (int j = 0; j < 4; ++j)
          ((u16*)C)[(size_t)(row + j) * ldc + col] = f2bf(acc[fp][fc][j] * alpha);
      } else {
        float* Cf = (float*)C + cstride * blockIdx.y;
#pragma unroll
        for (int j = 0; j < 4; ++j)
          Cf[(size_t)(row + j) * ldc + col] = acc[fp][fc][j] * alpha;
      }
    }
  }
}

// ---------------- split-K combine: bf16(p0+p1) ----------------

__global__ void combine_kernel(const float4* __restrict__ p0, const float4* __restrict__ p1,
                               u16x4* __restrict__ out) {
  int i = blockIdx.x * 256 + threadIdx.x;  // 8192 blocks x 256 -> 2M float4
  float4 a = p0[i], b = p1[i];
  u16x4 o;
  o[0] = f2bf(a.x + b.x); o[1] = f2bf(a.y + b.y);
  o[2] = f2bf(a.z + b.z); o[3] = f2bf(a.w + b.w);
  out[i] = o;
}

// ---------------- fused bias + row softmax, bf16 in place ----------------

__global__ __launch_bounds__(256) void softmax_bias_bf16_kernel(
    u16* __restrict__ S, const float2* __restrict__ cq, const float2* __restrict__ cr,
    const float* __restrict__ bwp, int qr0) {
  __shared__ float red[256];
  const int t = threadIdx.x;
  u16* row = S + (size_t)blockIdx.x * NK;
  const float2 cqv = cq[qr0 + blockIdx.x];
  const float bw = bwp[0];

  float l[32];
  float mx = -1e30f;
#pragma unroll
  for (int i = 0; i < 4; ++i) {
    int base = (i * 256 + t) * 8;
    u16x8 u = *(const u16x8*)&row[base];
#pragma unroll
    for (int j = 0; j < 8; ++j) {
      float x = bf2f(u[j]);
      float2 c = cr[base + j];
      float dx = cqv.x - c.x, dy = cqv.y - c.y;
      float lv = x - bw * sqrtf(dx * dx + dy * dy + 1e-8f);
      l[i * 8 + j] = lv;
      mx = fmaxf(mx, lv);
    }
  }
  red[t] = mx; __syncthreads();
  for (int s = 128; s > 0; s >>= 1) { if (t < s) red[t] = fmaxf(red[t], red[t + s]); __syncthreads(); }
  mx = red[0]; __syncthreads();

  float sum = 0.f;
#pragma unroll
  for (int i = 0; i < 32; ++i) { float e = __expf(l[i] - mx); l[i] = e; sum += e; }
  red[t] = sum; __syncthreads();
  for (int s = 128; s > 0; s >>= 1) { if (t < s) red[t] += red[t + s]; __syncthreads(); }
  float inv = 1.f / red[0];

#pragma unroll
  for (int i = 0; i < 4; ++i) {
    int base = (i * 256 + t) * 8;
    u16x8 o;
#pragma unroll
    for (int j = 0; j < 8; ++j) o[j] = f2bf(l[i * 8 + j] * inv);
    *(u16x8*)&row[base] = o;
  }
}

// ---------------- host ----------------

extern "C" void kernel_launch(void* const* d_in, const int* in_sizes, int n_in,
                              void* d_out, int out_size, void* d_ws, size_t ws_size,
                              hipStream_t stream) {
  const float* q  = (const float*)d_in[0];
  const float* k  = (const float*)d_in[1];
  const float* v  = (const float*)d_in[2];
  const float* rb = (const float*)d_in[3];
  const float* qb = (const float*)d_in[4];
  const float* Wq = (const float*)d_in[5];
  const float* Wk = (const float*)d_in[6];
  const float* Wv = (const float*)d_in[7];
  const float* Wp = (const float*)d_in[8];
  const float* bp = (const float*)d_in[9];
  const float* W1 = (const float*)d_in[10];
  const float* b1 = (const float*)d_in[11];
  const float* W2 = (const float*)d_in[12];
  const float* b2 = (const float*)d_in[13];
  float* out = (float*)d_out;

  char* p = (char*)d_ws;
  const size_t PROJB = (size_t)NQ * DIM * sizeof(u16);  // 16 MB
  u16* qbf = (u16*)p;            p += PROJB;
  u16* kbf = (u16*)p;            p += PROJB;
  u16* vbf = (u16*)p;            p += PROJB;
  u16* WqT = (u16*)p;            p += (size_t)DIM * DIM * 2;
  u16* WkT = (u16*)p;            p += (size_t)DIM * DIM * 2;
  u16* WvT = (u16*)p;            p += (size_t)DIM * DIM * 2;
  u16* WpT = (u16*)p;            p += (size_t)DIM * DIM * 2;
  u16* qh  = (u16*)p;            p += PROJB;
  u16* kh  = (u16*)p;            p += PROJB;
  u16* vhT = (u16*)p;            p += PROJB;
  float* cq  = (float*)p;        p += 2 * NQ * 4;
  float* cr  = (float*)p;        p += 2 * NK * 4;
  float* ps  = (float*)p;        p += 32 * DIM * 4;
  float* pq  = (float*)p;        p += 32 * DIM * 4;
  float* gfv = (float*)p;        p += DIM * 4;
  float* h1p = (float*)p;        p += 8 * 2048 * 4;
  float* bw  = (float*)p;        p += 64;
  size_t fixed_b = (size_t)(p - (char*)d_ws);

  int SR = 256;
  for (int cand = 8192; cand >= 256; cand >>= 1) {
    if (fixed_b + (size_t)cand * (NK + DIM) * 2 <= ws_size) { SR = cand; break; }
  }
  u16* Sbuf = (u16*)p;
  u16* Obuf = Sbuf + (size_t)SR * NK;

  // PV split-K f32 partials reuse dead regions (qbf+kbf, qh+kh: 32 MB each)
  float* pvp = (float*)qbf;   // partial 0 base; partial 1 at +cstride
  // note: cstride below maps partial1 into... use separate pointer scheme:
  // we launch one kernel with C=pvp0 and cstride such that y=1 lands at qh.
  // Simpler: two pointers must be contiguous-stride; qbf..kbf is 32MB and
  // qh..kh is 32MB but they are not adjacent. So launch PV twice (y-dim 1).

  // bias_weight = sigmoid(MLP(var(k, dim=0)))  [f32, tiny]
  var_partial_kernel<<<dim3(4, 32), 256, 0, stream>>>(k, ps, pq);
  gfv_kernel<<<4, 256, 0, stream>>>(ps, pq, gfv);
  h1_partial_kernel<<<dim3(8, 8), 256, 0, stream>>>(gfv, W1, h1p);
  bw_kernel<<<1, 256, 0, stream>>>(h1p, b1, W2, b2, bw);
  centers_kernel<<<32, 256, 0, stream>>>((const float4*)qb, (const float4*)rb,
                                         (float2*)cq, (float2*)cr);

  // convert inputs + weights to bf16 (weights transposed to [N][K])
  const int N4 = NQ * DIM / 4;
  f2bf_vec_kernel<<<2048, 256, 0, stream>>>((const float4*)q, (u16x4*)qbf, N4);
  f2bf_vec_kernel<<<2048, 256, 0, stream>>>((const float4*)k, (u16x4*)kbf, N4);
  f2bf_vec_kernel<<<2048, 256, 0, stream>>>((const float4*)v, (u16x4*)vbf, N4);
  wtrans_kernel<<<dim3(16, 16), 256, 0, stream>>>(Wq, WqT);
  wtrans_kernel<<<dim3(16, 16), 256, 0, stream>>>(Wk, WkT);
  wtrans_kernel<<<dim3(16, 16), 256, 0, stream>>>(Wv, WvT);
  wtrans_kernel<<<dim3(16, 16), 256, 0, stream>>>(Wp, WpT);

  // projections (128^2 kernel): qh = (q@Wq)*hd^-0.5, kh = k@Wk, vhT = (v@Wv)^T
  bgemm_kernel<1><<<dim3(DIM / TN, NQ / TM), 256, 0, stream>>>(
      qbf, WqT, qh, nullptr, NQ, DIM, DIM, DIM, 0.03125f);
  bgemm_kernel<1><<<dim3(DIM / TN, NK / TM), 256, 0, stream>>>(
      kbf, WkT, kh, nullptr, NK, DIM, DIM, DIM, 1.f);
  bgemm_kernel<2><<<dim3(DIM / TN, NK / TM), 256, 0, stream>>>(
      vbf, WvT, vhT, nullptr, NK, DIM, DIM, NK, 1.f);

  if (SR == 8192) {
    // ---- 256^2 8-phase path ----
    // S = qh @ kh^T  (M=N=8192, K=1024 -> NT=16, grid 32x32=1024)
    gemm256_kernel<0><<<dim3(1024, 1), 512, 0, stream>>>(
        qh, kh, Sbuf, 16, 32, 2048, 2048, NK, 0, 0, 1.f);
    softmax_bias_bf16_kernel<<<8192, 256, 0, stream>>>(
        Sbuf, (const float2*)cq, (const float2*)cr, bw, 0);
    // O_partial[kz] = P[:, kz*4096:+4096] @ vhT^T ; two launches (partials in
    // dead qbf/kbf and qh/kh regions, each 32 MB contiguous)
    float* pv0 = (float*)qbf;
    float* pv1 = (float*)qh;
    gemm256_kernel<1><<<dim3(128, 1), 512, 0, stream>>>(
        Sbuf, vhT, pv0, 64, 4, 16384, 16384, DIM, 0, 0, 1.f);
    gemm256_kernel<1><<<dim3(128, 1), 512, 0, stream>>>(
        Sbuf + 4096, vhT + 4096, pv1, 64, 4, 16384, 16384, DIM, 0, 0, 1.f);
    combine_kernel<<<8192, 256, 0, stream>>>(
        (const float4*)pv0, (const float4*)pv1, (u16x4*)Obuf);
    // out = O @ Wp + bp
    bgemm_kernel<0><<<dim3(DIM / TN, NQ / TM), 256, 0, stream>>>(
        Obuf, WpT, out, bp, NQ, DIM, DIM, DIM, 1.f);
  } else {
    // ---- fallback: round-2 striped path ----
    for (int s0 = 0; s0 < NQ; s0 += SR) {
      bgemm_kernel<1><<<dim3(NK / TN, SR / TM), 256, 0, stream>>>(
          qh + (size_t)s0 * DIM, kh, Sbuf, nullptr, SR, NK, DIM, NK, 1.f);
      softmax_bias_bf16_kernel<<<SR, 256, 0, stream>>>(
          Sbuf, (const float2*)cq, (const float2*)cr, bw, s0);
      bgemm_kernel<1><<<dim3(DIM / TN, SR / TM), 256, 0, stream>>>(
          Sbuf, vhT, Obuf, nullptr, SR, DIM, NK, DIM, 1.f);
      bgemm_kernel<0><<<dim3(DIM / TN, SR / TM), 256, 0, stream>>>(
          Obuf, WpT, out + (size_t)s0 * DIM, bp, SR, DIM, DIM, DIM, 1.f);
    }
  }
}

// Round 4
// 553.254 us; speedup vs baseline: 8.2474x; 1.1790x over previous
//
#include <hip/hip_runtime.h>
#include <math.h>

#define DIM 1024
#define NQ 8192
#define NK 8192

typedef unsigned short u16;
typedef __attribute__((ext_vector_type(8))) short short8;
typedef __attribute__((ext_vector_type(8))) u16 u16x8;
typedef __attribute__((ext_vector_type(4))) u16 u16x4;
typedef __attribute__((ext_vector_type(4))) float f32x4;
typedef __attribute__((address_space(1))) const unsigned int gu32;
typedef __attribute__((address_space(3))) unsigned int lu32;

__device__ inline u16 f2bf(float f) {
  unsigned u = __builtin_bit_cast(unsigned, f);
  u += 0x7fff + ((u >> 16) & 1);
  return (u16)(u >> 16);
}
__device__ inline float bf2f(u16 h) {
  unsigned u = ((unsigned)h) << 16;
  return __builtin_bit_cast(float, u);
}

// ---------------- small kernels: var -> MLP -> bias_weight ----------------

__global__ void var_partial_kernel(const float* __restrict__ k,
                                   float* __restrict__ ps, float* __restrict__ pq) {
  int col = blockIdx.x * 256 + threadIdx.x;
  int r0  = blockIdx.y * 256;
  float s = 0.f, q = 0.f;
  for (int r = 0; r < 256; ++r) {
    float x = k[(size_t)(r0 + r) * DIM + col];
    s += x; q += x * x;
  }
  ps[blockIdx.y * DIM + col] = s;
  pq[blockIdx.y * DIM + col] = q;
}

__global__ void gfv_kernel(const float* __restrict__ ps, const float* __restrict__ pq,
                           float* __restrict__ gfv) {
  int col = blockIdx.x * 256 + threadIdx.x;
  float s = 0.f, q = 0.f;
  for (int c = 0; c < 32; ++c) { s += ps[c * DIM + col]; q += pq[c * DIM + col]; }
  const float n = 8192.f;
  gfv[col] = (q - s * s / n) / (n - 1.f);  // unbiased var (ddof=1)
}

__global__ void h1_partial_kernel(const float* __restrict__ gfv, const float* __restrict__ W1,
                                  float* __restrict__ h1p) {
  int j  = blockIdx.x * 256 + threadIdx.x;
  int d0 = blockIdx.y * 128;
  float acc = 0.f;
  for (int d = 0; d < 128; ++d)
    acc += gfv[d0 + d] * W1[(size_t)(d0 + d) * 2048 + j];
  h1p[blockIdx.y * 2048 + j] = acc;
}

__global__ void bw_kernel(const float* __restrict__ h1p, const float* __restrict__ b1,
                          const float* __restrict__ W2, const float* __restrict__ b2,
                          float* __restrict__ bw) {
  __shared__ float red[256];
  int t = threadIdx.x;
  float acc = 0.f;
  for (int i = 0; i < 8; ++i) {
    int j = i * 256 + t;
    float h = b1[j];
    for (int c = 0; c < 8; ++c) h += h1p[c * 2048 + j];
    h = fmaxf(h, 0.f);
    acc += h * W2[j];
  }
  red[t] = acc; __syncthreads();
  for (int s = 128; s > 0; s >>= 1) { if (t < s) red[t] += red[t + s]; __syncthreads(); }
  if (t == 0) bw[0] = 1.f / (1.f + __expf(-(red[0] + b2[0])));
}

__global__ void centers_kernel(const float4* __restrict__ qb, const float4* __restrict__ rb,
                               float2* __restrict__ cq, float2* __restrict__ cr) {
  int i = blockIdx.x * 256 + threadIdx.x;
  float4 a = qb[i];
  cq[i] = make_float2(0.5f * (a.x + a.z), 0.5f * (a.y + a.w));
  float4 b = rb[i];
  cr[i] = make_float2(0.5f * (b.x + b.z), 0.5f * (b.y + b.w));
}

// ---------------- conversion kernels ----------------

__global__ void f2bf_vec_kernel(const float4* __restrict__ in, u16x4* __restrict__ out, int n4) {
  for (int i = blockIdx.x * 256 + threadIdx.x; i < n4; i += gridDim.x * 256) {
    float4 v = in[i];
    u16x4 o;
    o[0] = f2bf(v.x); o[1] = f2bf(v.y); o[2] = f2bf(v.z); o[3] = f2bf(v.w);
    out[i] = o;
  }
}

// transpose-convert 1024x1024 f32 W -> bf16 WT[n][k] = W[k][n]
__global__ __launch_bounds__(256) void wtrans_kernel(const float* __restrict__ W, u16* __restrict__ WT) {
  __shared__ float tile[64][65];
  const int t = threadIdx.x;
  const int kb = blockIdx.x * 64, nb = blockIdx.y * 64;
#pragma unroll
  for (int i = 0; i < 16; ++i) {
    int r = i * 4 + (t >> 6), c = t & 63;
    tile[c][r] = W[(size_t)(kb + r) * 1024 + nb + c];
  }
  __syncthreads();
#pragma unroll
  for (int i = 0; i < 16; ++i) {
    int n = i * 4 + (t >> 6), kk = t & 63;
    WT[(size_t)(nb + n) * 1024 + kb + kk] = f2bf(tile[n][kk]);
  }
}

// ---------------- 128x128 bf16 MFMA GEMM (projections / out-proj) ----------------
// C[M][N] = alpha*A[M][K] @ Bt[N][K]^T ; OUT: 0=f32+bias, 1=bf16, 2=bf16 transposed

#define TM 128
#define TN 128
#define TK 32

template <int OUT>
__global__ __launch_bounds__(256) void bgemm_kernel(
    const u16* __restrict__ A, const u16* __restrict__ Bt, void* __restrict__ C,
    const float* __restrict__ bias, int M, int N, int K, int ldc, float alpha) {
  __shared__ __align__(16) u16 As[TM * TK];
  __shared__ __align__(16) u16 Bs[TN * TK];

  const int t = threadIdx.x;
  const int l = t & 63;
  const int w = t >> 6;
  const int wm = w >> 1, wn = w & 1;
  const size_t row0 = (size_t)blockIdx.y * TM;
  const size_t col0 = (size_t)blockIdx.x * TN;

  f32x4 acc[4][4];
#pragma unroll
  for (int m = 0; m < 4; ++m)
#pragma unroll
    for (int n = 0; n < 4; ++n) acc[m][n] = (f32x4){0.f, 0.f, 0.f, 0.f};

  const int lane_r = l & 15;
  const int kgrp = (l >> 4) * 8;

  for (int k0 = 0; k0 < K; k0 += TK) {
#pragma unroll
    for (int j = 0; j < 2; ++j) {
      int idx = j * 256 + t;
      int r = idx >> 2, c8 = (idx & 3) << 3;
      __builtin_amdgcn_global_load_lds((gu32*)(A + (row0 + r) * K + k0 + c8),
                                       (lu32*)(As + idx * 8), 16, 0, 0);
      __builtin_amdgcn_global_load_lds((gu32*)(Bt + (col0 + r) * K + k0 + c8),
                                       (lu32*)(Bs + idx * 8), 16, 0, 0);
    }
    __syncthreads();

    short8 a[4], b[4];
#pragma unroll
    for (int m = 0; m < 4; ++m)
      a[m] = *(const short8*)&As[(wm * 64 + m * 16 + lane_r) * TK + kgrp];
#pragma unroll
    for (int n = 0; n < 4; ++n)
      b[n] = *(const short8*)&Bs[(wn * 64 + n * 16 + lane_r) * TK + kgrp];
#pragma unroll
    for (int m = 0; m < 4; ++m)
#pragma unroll
      for (int n = 0; n < 4; ++n)
        acc[m][n] = __builtin_amdgcn_mfma_f32_16x16x32_bf16(a[m], b[n], acc[m][n], 0, 0, 0);
    __syncthreads();
  }

#pragma unroll
  for (int m = 0; m < 4; ++m) {
#pragma unroll
    for (int n = 0; n < 4; ++n) {
      size_t col = col0 + wn * 64 + n * 16 + lane_r;
      size_t rbase = row0 + wm * 64 + m * 16 + (l >> 4) * 4;
      if (OUT == 0) {
        float bv = bias[col];
#pragma unroll
        for (int j = 0; j < 4; ++j)
          ((float*)C)[(rbase + j) * (size_t)ldc + col] = acc[m][n][j] * alpha + bv;
      } else if (OUT == 1) {
#pragma unroll
        for (int j = 0; j < 4; ++j)
          ((u16*)C)[(rbase + j) * (size_t)ldc + col] = f2bf(acc[m][n][j] * alpha);
      } else {
        u16x4 p;
#pragma unroll
        for (int j = 0; j < 4; ++j) p[j] = f2bf(acc[m][n][j] * alpha);
        *(u16x4*)&((u16*)C)[col * (size_t)ldc + rbase] = p;
      }
    }
  }
}

// ---------------- 256x256 4-phase bf16 MFMA GEMM (register-resident operands) ----
// C = alpha * A[M][K] @ Bt[N][K]^T. 512 threads = 8 waves (2M x 4N), BK=64.
// Per K-tile: P1 read A0+B0 / mfma A0B0; P2 read B1 / mfma A0B1;
//             P3 read A1 / mfma A1B0; P4 mfma A1B1. 24 ds_read_b128/wave/tile.
// Stages front-loaded: t+1's A0,B0 in P1 (4 calls), A1,B1 in P2 (4 calls).
// Waits: end-P1 vmcnt(4) [completes this tile's A1,B1]; end-P4 vmcnt(4)
// [completes next tile's A0,B0]. Never drains mid-loop.
// OUT: 0 = bf16 store; 1 = f32 store at C + cstride*blockIdx.y (split-K partial)

template <int VM>
__device__ __forceinline__ void waitvm() {
  if constexpr (VM == 4) asm volatile("s_waitcnt vmcnt(4)" ::: "memory");
  else asm volatile("s_waitcnt vmcnt(0)" ::: "memory");
}
#define FENCE asm volatile("" ::: "memory")

#define SGA(UNIT, KT, BUF)                                                          \
  __builtin_amdgcn_global_load_lds(                                                 \
      (gu32*)(Agp + (size_t)((UNIT) * 64) * ldaB + (size_t)(KT) * 128),             \
      (lu32*)(smem + (BUF) * 16384 + (UNIT) * 4096 + tid * 8), 16, 0, 0)

#define SGB(UNIT, KT, BUF)                                                          \
  do {                                                                              \
    int _rp = (UNIT) * 64 + rr;                                                     \
    size_t _row = (size_t)(bn0 + ((_rp >> 5) & 3) * 64 + (_rp >> 7) * 32 + (_rp & 31)); \
    __builtin_amdgcn_global_load_lds(                                               \
        (gu32*)(Bgp + _row * ldbB + (size_t)(KT) * 128),                            \
        (lu32*)(smem + 32768 + (BUF) * 16384 + (UNIT) * 4096 + tid * 8), 16, 0, 0); \
  } while (0)

#define RDA(MQ)                                                                     \
  _Pragma("unroll") for (int fr = 0; fr < 4; ++fr) {                                \
    af[fr][0] = *(const short8*)(smemc + bo + aRd + (MQ) * 8192 + fr * 2048 + koff0); \
    af[fr][1] = *(const short8*)(smemc + bo + aRd + (MQ) * 8192 + fr * 2048 + koff1); \
  }

#define RDB(NQ)                                                                     \
  _Pragma("unroll") for (int fc = 0; fc < 2; ++fc) {                                \
    bf[NQ][fc][0] = *(const short8*)(smemc + 65536 + bo + bRd + (NQ) * 16384 + fc * 2048 + koff0); \
    bf[NQ][fc][1] = *(const short8*)(smemc + 65536 + bo + bRd + (NQ) * 16384 + fc * 2048 + koff1); \
  }

#define MMQ(MQ, NQ)                                                                 \
  _Pragma("unroll") for (int fr = 0; fr < 4; ++fr)                                  \
  _Pragma("unroll") for (int fc = 0; fc < 2; ++fc) {                                \
    acc[(MQ) * 4 + fr][(NQ) * 2 + fc] = __builtin_amdgcn_mfma_f32_16x16x32_bf16(    \
        af[fr][0], bf[NQ][fc][0], acc[(MQ) * 4 + fr][(NQ) * 2 + fc], 0, 0, 0);      \
    acc[(MQ) * 4 + fr][(NQ) * 2 + fc] = __builtin_amdgcn_mfma_f32_16x16x32_bf16(    \
        af[fr][1], bf[NQ][fc][1], acc[(MQ) * 4 + fr][(NQ) * 2 + fc], 0, 0, 0);      \
  }

#define BARRIER do { FENCE; __builtin_amdgcn_s_barrier(); FENCE; } while (0)

template <int OUT>
__global__ __launch_bounds__(512, 2) void gemm256_kernel(
    const u16* __restrict__ A, const u16* __restrict__ Bt, void* __restrict__ C,
    int NT, int nTn, int tmb, size_t ldaB, size_t ldbB, int ldc, size_t kspanB,
    size_t cstride, float alpha) {
  __shared__ __align__(16) u16 smem[65536];  // 128 KiB
  const char* smemc = (const char*)smem;

  const int tid = threadIdx.x;
  const int l = tid & 63;
  const int wid = tid >> 6;
  const int wm = wid >> 2, wn = wid & 3;
  const int lane_r = l & 15;
  const int kq = l >> 4;
  const int rr = tid >> 3;

  // XCD-chunked swizzle, tn-inner: xcd owns tm band [xcd*tmb, +tmb)
  const int bid = blockIdx.x;
  const int xcd = bid & 7;
  const int c = bid >> 3;
  const int tm = xcd * tmb + (c % tmb);
  const int tn = c / tmb;
  const int am0 = tm * 256, bn0 = tn * 256;
  const size_t kglob = kspanB * blockIdx.y;

  // XOR-swizzled k-offsets for ds_read (cancelled by pre-swizzled global src)
  const int kx = (lane_r & 7) << 4;
  const int koff0 = (kq << 4) ^ kx;
  const int koff1 = (64 | (kq << 4)) ^ kx;
  const int aRd = (wm * 128 + lane_r) * 128;  // byte
  const int bRd = (wn * 32 + lane_r) * 128;   // byte

  const int scol = ((tid & 7) ^ ((tid >> 3) & 7)) << 4;
  const char* Agp = (const char*)A + (size_t)(am0 + rr) * ldaB + kglob + scol;
  const char* Bgp = (const char*)Bt + kglob + scol;

  f32x4 acc[8][4];
#pragma unroll
  for (int i = 0; i < 8; ++i)
#pragma unroll
    for (int j = 0; j < 4; ++j) acc[i][j] = (f32x4){0.f, 0.f, 0.f, 0.f};

  short8 af[4][2], bf[2][2][2];

  // prologue: tile0 -> buf0 (A0,B0 first, then A1,B1)
  SGA(0, 0, 0); SGA(2, 0, 0); SGB(0, 0, 0); SGB(1, 0, 0);
  SGA(1, 0, 0); SGA(3, 0, 0); SGB(2, 0, 0); SGB(3, 0, 0);
  waitvm<4>();
  BARRIER;

  for (int t = 0; t < NT; ++t) {
    const int bo = (t & 1) * 32768;
    const int nb = (t & 1) ^ 1;
    const bool more = (t + 1 < NT);
    // ---- P1: read A0,B0; stage t+1 A0,B0 ----
    RDA(0); RDB(0);
    if (more) { SGA(0, t + 1, nb); SGA(2, t + 1, nb); SGB(0, t + 1, nb); SGB(1, t + 1, nb); }
    BARRIER;
    __builtin_amdgcn_s_setprio(1); MMQ(0, 0); __builtin_amdgcn_s_setprio(0);
    if (more) waitvm<4>(); else waitvm<0>();
    BARRIER;
    // ---- P2: read B1; stage t+1 A1,B1 ----
    RDB(1);
    if (more) { SGA(1, t + 1, nb); SGA(3, t + 1, nb); SGB(2, t + 1, nb); SGB(3, t + 1, nb); }
    BARRIER;
    __builtin_amdgcn_s_setprio(1); MMQ(0, 1); __builtin_amdgcn_s_setprio(0);
    BARRIER;
    // ---- P3: read A1 ----
    RDA(1);
    BARRIER;
    __builtin_amdgcn_s_setprio(1); MMQ(1, 0); __builtin_amdgcn_s_setprio(0);
    BARRIER;
    // ---- P4: mfma only ----
    __builtin_amdgcn_s_setprio(1); MMQ(1, 1); __builtin_amdgcn_s_setprio(0);
    if (more) waitvm<4>();
    BARRIER;
  }

  // epilogue: 16x16x32 C layout: col = lane&15, row = kq*4 + j
#pragma unroll
  for (int fp = 0; fp < 8; ++fp) {
#pragma unroll
    for (int fc = 0; fc < 4; ++fc) {
      int row = am0 + wm * 128 + fp * 16 + kq * 4;
      int col = bn0 + wn * 64 + fc * 16 + lane_r;
      if (OUT == 0) {
#pragma unroll
        for (int j = 0; j < 4; ++j)
          ((u16*)C)[(size_t)(row + j) * ldc + col] = f2bf(acc[fp][fc][j] * alpha);
      } else {
        float* Cf = (float*)C + cstride * blockIdx.y;
#pragma unroll
        for (int j = 0; j < 4; ++j)
          Cf[(size_t)(row + j) * ldc + col] = acc[fp][fc][j] * alpha;
      }
    }
  }
}

// ---------------- split-K combine: bf16(p0+p1) ----------------

__global__ void combine_kernel(const float4* __restrict__ p0, const float4* __restrict__ p1,
                               u16x4* __restrict__ out) {
  int i = blockIdx.x * 256 + threadIdx.x;  // 8192 blocks -> 2M float4
  float4 a = p0[i], b = p1[i];
  u16x4 o;
  o[0] = f2bf(a.x + b.x); o[1] = f2bf(a.y + b.y);
  o[2] = f2bf(a.z + b.z); o[3] = f2bf(a.w + b.w);
  out[i] = o;
}

// ---------------- fused bias + row softmax, bf16 in place ----------------

__global__ __launch_bounds__(256) void softmax_bias_bf16_kernel(
    u16* __restrict__ S, const float2* __restrict__ cq, const float2* __restrict__ cr,
    const float* __restrict__ bwp, int qr0) {
  __shared__ float red[256];
  const int t = threadIdx.x;
  u16* row = S + (size_t)blockIdx.x * NK;
  const float2 cqv = cq[qr0 + blockIdx.x];
  const float bw = bwp[0];

  float l[32];
  float mx = -1e30f;
#pragma unroll
  for (int i = 0; i < 4; ++i) {
    int base = (i * 256 + t) * 8;
    u16x8 u = *(const u16x8*)&row[base];
#pragma unroll
    for (int j = 0; j < 8; ++j) {
      float x = bf2f(u[j]);
      float2 c = cr[base + j];
      float dx = cqv.x - c.x, dy = cqv.y - c.y;
      float lv = x - bw * sqrtf(dx * dx + dy * dy + 1e-8f);
      l[i * 8 + j] = lv;
      mx = fmaxf(mx, lv);
    }
  }
  red[t] = mx; __syncthreads();
  for (int s = 128; s > 0; s >>= 1) { if (t < s) red[t] = fmaxf(red[t], red[t + s]); __syncthreads(); }
  mx = red[0]; __syncthreads();

  float sum = 0.f;
#pragma unroll
  for (int i = 0; i < 32; ++i) { float e = __expf(l[i] - mx); l[i] = e; sum += e; }
  red[t] = sum; __syncthreads();
  for (int s = 128; s > 0; s >>= 1) { if (t < s) red[t] += red[t + s]; __syncthreads(); }
  float inv = 1.f / red[0];

#pragma unroll
  for (int i = 0; i < 4; ++i) {
    int base = (i * 256 + t) * 8;
    u16x8 o;
#pragma unroll
    for (int j = 0; j < 8; ++j) o[j] = f2bf(l[i * 8 + j] * inv);
    *(u16x8*)&row[base] = o;
  }
}

// ---------------- host ----------------

extern "C" void kernel_launch(void* const* d_in, const int* in_sizes, int n_in,
                              void* d_out, int out_size, void* d_ws, size_t ws_size,
                              hipStream_t stream) {
  const float* q  = (const float*)d_in[0];
  const float* k  = (const float*)d_in[1];
  const float* v  = (const float*)d_in[2];
  const float* rb = (const float*)d_in[3];
  const float* qb = (const float*)d_in[4];
  const float* Wq = (const float*)d_in[5];
  const float* Wk = (const float*)d_in[6];
  const float* Wv = (const float*)d_in[7];
  const float* Wp = (const float*)d_in[8];
  const float* bp = (const float*)d_in[9];
  const float* W1 = (const float*)d_in[10];
  const float* b1 = (const float*)d_in[11];
  const float* W2 = (const float*)d_in[12];
  const float* b2 = (const float*)d_in[13];
  float* out = (float*)d_out;

  // Layout: qbf|kbf|vbf|qh form a 64 MB contiguous region, all dead by PV
  // time -> reused as the two 32 MB f32 split-K partials.
  char* p = (char*)d_ws;
  const size_t PROJB = (size_t)NQ * DIM * sizeof(u16);  // 16 MB
  u16* qbf = (u16*)p;            p += PROJB;
  u16* kbf = (u16*)p;            p += PROJB;
  u16* vbf = (u16*)p;            p += PROJB;
  u16* qh  = (u16*)p;            p += PROJB;
  u16* kh  = (u16*)p;            p += PROJB;
  u16* vhT = (u16*)p;            p += PROJB;
  u16* WqT = (u16*)p;            p += (size_t)DIM * DIM * 2;
  u16* WkT = (u16*)p;            p += (size_t)DIM * DIM * 2;
  u16* WvT = (u16*)p;            p += (size_t)DIM * DIM * 2;
  u16* WpT = (u16*)p;            p += (size_t)DIM * DIM * 2;
  float* cq  = (float*)p;        p += 2 * NQ * 4;
  float* cr  = (float*)p;        p += 2 * NK * 4;
  float* ps  = (float*)p;        p += 32 * DIM * 4;
  float* pq  = (float*)p;        p += 32 * DIM * 4;
  float* gfv = (float*)p;        p += DIM * 4;
  float* h1p = (float*)p;        p += 8 * 2048 * 4;
  float* bw  = (float*)p;        p += 64;
  size_t fixed_b = (size_t)(p - (char*)d_ws);

  int SR = 256;
  for (int cand = 8192; cand >= 256; cand >>= 1) {
    if (fixed_b + (size_t)cand * (NK + DIM) * 2 <= ws_size) { SR = cand; break; }
  }
  u16* Sbuf = (u16*)p;
  u16* Obuf = Sbuf + (size_t)SR * NK;

  // bias_weight = sigmoid(MLP(var(k, dim=0)))  [f32, tiny]
  var_partial_kernel<<<dim3(4, 32), 256, 0, stream>>>(k, ps, pq);
  gfv_kernel<<<4, 256, 0, stream>>>(ps, pq, gfv);
  h1_partial_kernel<<<dim3(8, 8), 256, 0, stream>>>(gfv, W1, h1p);
  bw_kernel<<<1, 256, 0, stream>>>(h1p, b1, W2, b2, bw);
  centers_kernel<<<32, 256, 0, stream>>>((const float4*)qb, (const float4*)rb,
                                         (float2*)cq, (float2*)cr);

  // convert inputs + weights to bf16 (weights transposed to [N][K])
  const int N4 = NQ * DIM / 4;
  f2bf_vec_kernel<<<2048, 256, 0, stream>>>((const float4*)q, (u16x4*)qbf, N4);
  f2bf_vec_kernel<<<2048, 256, 0, stream>>>((const float4*)k, (u16x4*)kbf, N4);
  f2bf_vec_kernel<<<2048, 256, 0, stream>>>((const float4*)v, (u16x4*)vbf, N4);
  wtrans_kernel<<<dim3(16, 16), 256, 0, stream>>>(Wq, WqT);
  wtrans_kernel<<<dim3(16, 16), 256, 0, stream>>>(Wk, WkT);
  wtrans_kernel<<<dim3(16, 16), 256, 0, stream>>>(Wv, WvT);
  wtrans_kernel<<<dim3(16, 16), 256, 0, stream>>>(Wp, WpT);

  // projections (128^2 kernel): qh = (q@Wq)*hd^-0.5, kh = k@Wk, vhT = (v@Wv)^T
  bgemm_kernel<1><<<dim3(DIM / TN, NQ / TM), 256, 0, stream>>>(
      qbf, WqT, qh, nullptr, NQ, DIM, DIM, DIM, 0.03125f);
  bgemm_kernel<1><<<dim3(DIM / TN, NK / TM), 256, 0, stream>>>(
      kbf, WkT, kh, nullptr, NK, DIM, DIM, DIM, 1.f);
  bgemm_kernel<2><<<dim3(DIM / TN, NK / TM), 256, 0, stream>>>(
      vbf, WvT, vhT, nullptr, NK, DIM, DIM, NK, 1.f);

  if (SR == 8192) {
    // ---- 256^2 4-phase path ----
    // S = qh @ kh^T : M=N=8192, K=1024, grid 32x32, NT=16
    gemm256_kernel<0><<<dim3(1024, 1), 512, 0, stream>>>(
        qh, kh, Sbuf, 16, 32, 4, 2048, 2048, NK, 0, 0, 1.f);
    softmax_bias_bf16_kernel<<<8192, 256, 0, stream>>>(
        Sbuf, (const float2*)cq, (const float2*)cr, bw, 0);
    // O = P @ vh, split-K=2 in one launch (y in {0,1}), f32 partials into
    // the dead 64 MB qbf..qh region, stride 8192*1024 floats
    float* pv0 = (float*)qbf;
    gemm256_kernel<1><<<dim3(128, 2), 512, 0, stream>>>(
        Sbuf, vhT, pv0, 64, 4, 4, 16384, 16384, DIM, 8192, (size_t)8192 * 1024, 1.f);
    combine_kernel<<<8192, 256, 0, stream>>>(
        (const float4*)pv0, (const float4*)(pv0 + (size_t)8192 * 1024), (u16x4*)Obuf);
    // out = O @ Wp + bp
    bgemm_kernel<0><<<dim3(DIM / TN, NQ / TM), 256, 0, stream>>>(
        Obuf, WpT, out, bp, NQ, DIM, DIM, DIM, 1.f);
  } else {
    // ---- fallback: striped path ----
    for (int s0 = 0; s0 < NQ; s0 += SR) {
      bgemm_kernel<1><<<dim3(NK / TN, SR / TM), 256, 0, stream>>>(
          qh + (size_t)s0 * DIM, kh, Sbuf, nullptr, SR, NK, DIM, NK, 1.f);
      softmax_bias_bf16_kernel<<<SR, 256, 0, stream>>>(
          Sbuf, (const float2*)cq, (const float2*)cr, bw, s0);
      bgemm_kernel<1><<<dim3(DIM / TN, SR / TM), 256, 0, stream>>>(
          Sbuf, vhT, Obuf, nullptr, SR, DIM, NK, DIM, 1.f);
      bgemm_kernel<0><<<dim3(DIM / TN, SR / TM), 256, 0, stream>>>(
          Obuf, WpT, out + (size_t)s0 * DIM, bp, SR, DIM, DIM, DIM, 1.f);
    }
  }
}

// Round 5
// 513.985 us; speedup vs baseline: 8.8775x; 1.0764x over previous
//
#include <hip/hip_runtime.h>
#include <math.h>

#define DIM 1024
#define NQ 8192
#define NK 8192

typedef unsigned short u16;
typedef __attribute__((ext_vector_type(8))) short short8;
typedef __attribute__((ext_vector_type(8))) u16 u16x8;
typedef __attribute__((ext_vector_type(4))) u16 u16x4;
typedef __attribute__((ext_vector_type(4))) float f32x4;
typedef __attribute__((address_space(1))) const unsigned int gu32;
typedef __attribute__((address_space(3))) unsigned int lu32;

__device__ inline u16 f2bf(float f) {
  unsigned u = __builtin_bit_cast(unsigned, f);
  u += 0x7fff + ((u >> 16) & 1);
  return (u16)(u >> 16);
}
__device__ inline float bf2f(u16 h) {
  unsigned u = ((unsigned)h) << 16;
  return __builtin_bit_cast(float, u);
}

// ---------------- small kernels: var -> MLP -> bias_weight ----------------

__global__ void var_partial_kernel(const float* __restrict__ k,
                                   float* __restrict__ ps, float* __restrict__ pq) {
  int col = blockIdx.x * 256 + threadIdx.x;
  int r0  = blockIdx.y * 256;
  float s = 0.f, q = 0.f;
  for (int r = 0; r < 256; ++r) {
    float x = k[(size_t)(r0 + r) * DIM + col];
    s += x; q += x * x;
  }
  ps[blockIdx.y * DIM + col] = s;
  pq[blockIdx.y * DIM + col] = q;
}

__global__ void gfv_kernel(const float* __restrict__ ps, const float* __restrict__ pq,
                           float* __restrict__ gfv) {
  int col = blockIdx.x * 256 + threadIdx.x;
  float s = 0.f, q = 0.f;
  for (int c = 0; c < 32; ++c) { s += ps[c * DIM + col]; q += pq[c * DIM + col]; }
  const float n = 8192.f;
  gfv[col] = (q - s * s / n) / (n - 1.f);  // unbiased var (ddof=1)
}

__global__ void h1_partial_kernel(const float* __restrict__ gfv, const float* __restrict__ W1,
                                  float* __restrict__ h1p) {
  int j  = blockIdx.x * 256 + threadIdx.x;
  int d0 = blockIdx.y * 128;
  float acc = 0.f;
  for (int d = 0; d < 128; ++d)
    acc += gfv[d0 + d] * W1[(size_t)(d0 + d) * 2048 + j];
  h1p[blockIdx.y * 2048 + j] = acc;
}

__global__ void bw_kernel(const float* __restrict__ h1p, const float* __restrict__ b1,
                          const float* __restrict__ W2, const float* __restrict__ b2,
                          float* __restrict__ bw) {
  __shared__ float red[256];
  int t = threadIdx.x;
  float acc = 0.f;
  for (int i = 0; i < 8; ++i) {
    int j = i * 256 + t;
    float h = b1[j];
    for (int c = 0; c < 8; ++c) h += h1p[c * 2048 + j];
    h = fmaxf(h, 0.f);
    acc += h * W2[j];
  }
  red[t] = acc; __syncthreads();
  for (int s = 128; s > 0; s >>= 1) { if (t < s) red[t] += red[t + s]; __syncthreads(); }
  if (t == 0) bw[0] = 1.f / (1.f + __expf(-(red[0] + b2[0])));
}

__global__ void centers_kernel(const float4* __restrict__ qb, const float4* __restrict__ rb,
                               float2* __restrict__ cq, float2* __restrict__ cr) {
  int i = blockIdx.x * 256 + threadIdx.x;
  float4 a = qb[i];
  cq[i] = make_float2(0.5f * (a.x + a.z), 0.5f * (a.y + a.w));
  float4 b = rb[i];
  cr[i] = make_float2(0.5f * (b.x + b.z), 0.5f * (b.y + b.w));
}

// ---------------- conversion kernels ----------------

__global__ void f2bf_vec_kernel(const float4* __restrict__ in, u16x4* __restrict__ out, int n4) {
  for (int i = blockIdx.x * 256 + threadIdx.x; i < n4; i += gridDim.x * 256) {
    float4 v = in[i];
    u16x4 o;
    o[0] = f2bf(v.x); o[1] = f2bf(v.y); o[2] = f2bf(v.z); o[3] = f2bf(v.w);
    out[i] = o;
  }
}

// transpose-convert 1024x1024 f32 W -> bf16 WT[n][k] = W[k][n]
__global__ __launch_bounds__(256) void wtrans_kernel(const float* __restrict__ W, u16* __restrict__ WT) {
  __shared__ float tile[64][65];
  const int t = threadIdx.x;
  const int kb = blockIdx.x * 64, nb = blockIdx.y * 64;
#pragma unroll
  for (int i = 0; i < 16; ++i) {
    int r = i * 4 + (t >> 6), c = t & 63;
    tile[c][r] = W[(size_t)(kb + r) * 1024 + nb + c];
  }
  __syncthreads();
#pragma unroll
  for (int i = 0; i < 16; ++i) {
    int n = i * 4 + (t >> 6), kk = t & 63;
    WT[(size_t)(nb + n) * 1024 + kb + kk] = f2bf(tile[n][kk]);
  }
}

// ---------------- 128x128 bf16 MFMA GEMM (projections / out-proj) ----------------
// C[M][N] = alpha*A[M][K] @ Bt[N][K]^T ; OUT: 0=f32+bias, 1=bf16, 2=bf16 transposed

#define TM 128
#define TN 128
#define TK 32

template <int OUT>
__global__ __launch_bounds__(256) void bgemm_kernel(
    const u16* __restrict__ A, const u16* __restrict__ Bt, void* __restrict__ C,
    const float* __restrict__ bias, int M, int N, int K, int ldc, float alpha) {
  __shared__ __align__(16) u16 As[TM * TK];
  __shared__ __align__(16) u16 Bs[TN * TK];

  const int t = threadIdx.x;
  const int l = t & 63;
  const int w = t >> 6;
  const int wm = w >> 1, wn = w & 1;
  const size_t row0 = (size_t)blockIdx.y * TM;
  const size_t col0 = (size_t)blockIdx.x * TN;

  f32x4 acc[4][4];
#pragma unroll
  for (int m = 0; m < 4; ++m)
#pragma unroll
    for (int n = 0; n < 4; ++n) acc[m][n] = (f32x4){0.f, 0.f, 0.f, 0.f};

  const int lane_r = l & 15;
  const int kgrp = (l >> 4) * 8;

  for (int k0 = 0; k0 < K; k0 += TK) {
#pragma unroll
    for (int j = 0; j < 2; ++j) {
      int idx = j * 256 + t;
      int r = idx >> 2, c8 = (idx & 3) << 3;
      __builtin_amdgcn_global_load_lds((gu32*)(A + (row0 + r) * K + k0 + c8),
                                       (lu32*)(As + idx * 8), 16, 0, 0);
      __builtin_amdgcn_global_load_lds((gu32*)(Bt + (col0 + r) * K + k0 + c8),
                                       (lu32*)(Bs + idx * 8), 16, 0, 0);
    }
    __syncthreads();

    short8 a[4], b[4];
#pragma unroll
    for (int m = 0; m < 4; ++m)
      a[m] = *(const short8*)&As[(wm * 64 + m * 16 + lane_r) * TK + kgrp];
#pragma unroll
    for (int n = 0; n < 4; ++n)
      b[n] = *(const short8*)&Bs[(wn * 64 + n * 16 + lane_r) * TK + kgrp];
#pragma unroll
    for (int m = 0; m < 4; ++m)
#pragma unroll
      for (int n = 0; n < 4; ++n)
        acc[m][n] = __builtin_amdgcn_mfma_f32_16x16x32_bf16(a[m], b[n], acc[m][n], 0, 0, 0);
    __syncthreads();
  }

#pragma unroll
  for (int m = 0; m < 4; ++m) {
#pragma unroll
    for (int n = 0; n < 4; ++n) {
      size_t col = col0 + wn * 64 + n * 16 + lane_r;
      size_t rbase = row0 + wm * 64 + m * 16 + (l >> 4) * 4;
      if (OUT == 0) {
        float bv = bias[col];
#pragma unroll
        for (int j = 0; j < 4; ++j)
          ((float*)C)[(rbase + j) * (size_t)ldc + col] = acc[m][n][j] * alpha + bv;
      } else if (OUT == 1) {
#pragma unroll
        for (int j = 0; j < 4; ++j)
          ((u16*)C)[(rbase + j) * (size_t)ldc + col] = f2bf(acc[m][n][j] * alpha);
      } else {
        u16x4 p;
#pragma unroll
        for (int j = 0; j < 4; ++j) p[j] = f2bf(acc[m][n][j] * alpha);
        *(u16x4*)&((u16*)C)[col * (size_t)ldc + rbase] = p;
      }
    }
  }
}

// ---------------- 256x256 bf16 MFMA GEMM, 8-cluster read-ahead pipeline ----------
// C = alpha * A[M][K] @ Bt[N][K]^T. 512 threads = 8 waves (2M x 4N), BK=64.
// Per K-tile: 8 clusters x 8 MFMA. Cluster order over (MQ,kk) gray-coded:
//   c0(0,0,k0) c1(0,1,k0) c2(1,1,k0) c3(1,0,k0) c4(1,0,k1) c5(1,1,k1) c6(0,1,k1) c7(0,0,k1)
// A: ping-pong sets afP/afQ (read 1-2 clusters ahead); B: bf[NQ][kk] all resident.
// Stages (8 calls for tile t+1) front-loaded 2/cluster in c0..c3.
// Sync: end-c6 {vmcnt(4) covers t+1's A0,B0; barrier} -> c7 reads next buffer;
//       end-c7 {vmcnt(0), loads aged >=4 clusters; barrier} = tile boundary.
// Never a hard drain on young loads; 2 barriers/K-tile.
// OUT: 0 = bf16 store; 1 = f32 store at C + cstride*blockIdx.y (split-K partial)

template <int VM>
__device__ __forceinline__ void waitvm() {
  if constexpr (VM == 4) asm volatile("s_waitcnt vmcnt(4)" ::: "memory");
  else asm volatile("s_waitcnt vmcnt(0)" ::: "memory");
}
#define FENCE asm volatile("" ::: "memory")
#define BARRIER do { FENCE; __builtin_amdgcn_s_barrier(); FENCE; } while (0)

#define SGA(UNIT, KT, BUF)                                                          \
  __builtin_amdgcn_global_load_lds(                                                 \
      (gu32*)(Agp + (size_t)((UNIT) * 64) * ldaB + (size_t)(KT) * 128),             \
      (lu32*)(smem + (BUF) * 16384 + (UNIT) * 4096 + tid * 8), 16, 0, 0)

#define SGB(UNIT, KT, BUF)                                                          \
  do {                                                                              \
    int _rp = (UNIT) * 64 + rr;                                                     \
    size_t _row = (size_t)(bn0 + ((_rp >> 5) & 3) * 64 + (_rp >> 7) * 32 + (_rp & 31)); \
    __builtin_amdgcn_global_load_lds(                                               \
        (gu32*)(Bgp + _row * ldbB + (size_t)(KT) * 128),                            \
        (lu32*)(smem + 32768 + (BUF) * 16384 + (UNIT) * 4096 + tid * 8), 16, 0, 0); \
  } while (0)

#define RDA4(DST, BO, MQ, KO)                                                       \
  _Pragma("unroll") for (int fr = 0; fr < 4; ++fr)                                  \
    DST[fr] = *(const short8*)(smemc + (BO) + aRd + (MQ) * 8192 + fr * 2048 + (KO));

#define RDB2(NQ_, KK, BO, KO)                                                       \
  _Pragma("unroll") for (int fc = 0; fc < 2; ++fc)                                  \
    bf[NQ_][KK][fc] = *(const short8*)(smemc + 65536 + (BO) + bRd + (NQ_) * 16384 + fc * 2048 + (KO));

#define MM8(AF, MQ, NQ_, KK)                                                        \
  do {                                                                              \
    __builtin_amdgcn_s_setprio(1);                                                  \
    _Pragma("unroll") for (int fr = 0; fr < 4; ++fr)                                \
    _Pragma("unroll") for (int fc = 0; fc < 2; ++fc)                                \
      acc[(MQ) * 4 + fr][(NQ_) * 2 + fc] = __builtin_amdgcn_mfma_f32_16x16x32_bf16( \
          AF[fr], bf[NQ_][KK][fc], acc[(MQ) * 4 + fr][(NQ_) * 2 + fc], 0, 0, 0);    \
    __builtin_amdgcn_s_setprio(0);                                                  \
  } while (0)

template <int OUT>
__global__ __launch_bounds__(512, 2) void gemm256_kernel(
    const u16* __restrict__ A, const u16* __restrict__ Bt, void* __restrict__ C,
    int NT, int nTn, int tmb, size_t ldaB, size_t ldbB, int ldc, size_t kspanB,
    size_t cstride, float alpha) {
  __shared__ __align__(16) u16 smem[65536];  // 128 KiB
  const char* smemc = (const char*)smem;

  const int tid = threadIdx.x;
  const int l = tid & 63;
  const int wid = tid >> 6;
  const int wm = wid >> 2, wn = wid & 3;
  const int lane_r = l & 15;
  const int kq = l >> 4;
  const int rr = tid >> 3;

  // XCD-chunked swizzle, tn-inner: xcd owns tm band [xcd*tmb, +tmb)
  const int bid = blockIdx.x;
  const int xcd = bid & 7;
  const int c = bid >> 3;
  const int tm = xcd * tmb + (c % tmb);
  const int tn = c / tmb;
  const int am0 = tm * 256, bn0 = tn * 256;
  const size_t kglob = kspanB * blockIdx.y;

  // XOR-swizzled k-offsets for ds_read (cancelled by pre-swizzled global src)
  const int kx = (lane_r & 7) << 4;
  const int koff0 = (kq << 4) ^ kx;
  const int koff1 = (64 | (kq << 4)) ^ kx;
  const int aRd = (wm * 128 + lane_r) * 128;  // byte
  const int bRd = (wn * 32 + lane_r) * 128;   // byte

  const int scol = ((tid & 7) ^ ((tid >> 3) & 7)) << 4;
  const char* Agp = (const char*)A + (size_t)(am0 + rr) * ldaB + kglob + scol;
  const char* Bgp = (const char*)Bt + kglob + scol;

  f32x4 acc[8][4];
#pragma unroll
  for (int i = 0; i < 8; ++i)
#pragma unroll
    for (int j = 0; j < 4; ++j) acc[i][j] = (f32x4){0.f, 0.f, 0.f, 0.f};

  short8 afP[4], afQ[4], bf[2][2][2];

  // prologue: tile0 -> buf0 in deadline order (A0,B0 first)
  SGA(0, 0, 0); SGA(2, 0, 0); SGB(0, 0, 0); SGB(1, 0, 0);
  SGB(2, 0, 0); SGB(3, 0, 0); SGA(1, 0, 0); SGA(3, 0, 0);
  waitvm<0>();
  BARRIER;
  RDA4(afP, 0, 0, koff0);   // A0 k0
  RDB2(0, 0, 0, koff0);     // B0 k0

  for (int t = 0; t < NT; ++t) {
    const int bo = (t & 1) * 32768;
    const int nbo = bo ^ 32768;
    const int nb = (t & 1) ^ 1;
    const bool more = (t + 1 < NT);
    // c0: (0,0,k0)
    if (more) { SGA(0, t + 1, nb); SGA(2, t + 1, nb); }
    RDB2(1, 0, bo, koff0);            // B1 k0 (for c1)
    MM8(afP, 0, 0, 0);
    // c1: (0,1,k0)
    if (more) { SGB(0, t + 1, nb); SGB(1, t + 1, nb); }
    RDA4(afQ, bo, 1, koff0);          // A1 k0 (for c2)
    MM8(afP, 0, 1, 0);
    // c2: (1,1,k0)
    if (more) { SGB(2, t + 1, nb); SGB(3, t + 1, nb); }
    RDB2(0, 1, bo, koff1);            // B0 k1 (for c4)
    MM8(afQ, 1, 1, 0);
    // c3: (1,0,k0)
    if (more) { SGA(1, t + 1, nb); SGA(3, t + 1, nb); }
    RDA4(afP, bo, 1, koff1);          // A1 k1 (for c4)  [afP dead since c1]
    MM8(afQ, 1, 0, 0);
    // c4: (1,0,k1)
    RDB2(1, 1, bo, koff1);            // B1 k1 (for c5)
    MM8(afP, 1, 0, 1);
    // c5: (1,1,k1)
    RDA4(afQ, bo, 0, koff1);          // A0 k1 (for c6)  [afQ dead since c3]
    MM8(afP, 1, 1, 1);
    // c6: (0,1,k1)
    MM8(afQ, 0, 1, 1);
    waitvm<4>();                      // completes t+1's A0,B0 (staged c0,c1)
    BARRIER;                          // cross-wave: next buffer A0,B0 readable
    // c7: (0,0,k1)  + boundary read-ahead from next buffer
    if (more) { RDA4(afP, nbo, 0, koff0); RDB2(0, 0, nbo, koff0); }
    MM8(afQ, 0, 0, 1);
    waitvm<0>();                      // completes t+1's B1,A1 (staged c2,c3; aged ~4 clusters)
    BARRIER;                          // tile boundary
  }

  // epilogue: 16x16x32 C layout: col = lane&15, row = kq*4 + j
#pragma unroll
  for (int fp = 0; fp < 8; ++fp) {
#pragma unroll
    for (int fc = 0; fc < 4; ++fc) {
      int row = am0 + wm * 128 + fp * 16 + kq * 4;
      int col = bn0 + wn * 64 + fc * 16 + lane_r;
      if (OUT == 0) {
#pragma unroll
        for (int j = 0; j < 4; ++j)
          ((u16*)C)[(size_t)(row + j) * ldc + col] = f2bf(acc[fp][fc][j] * alpha);
      } else {
        float* Cf = (float*)C + cstride * blockIdx.y;
#pragma unroll
        for (int j = 0; j < 4; ++j)
          Cf[(size_t)(row + j) * ldc + col] = acc[fp][fc][j] * alpha;
      }
    }
  }
}

// ---------------- split-K combine: bf16(p0+p1) ----------------

__global__ void combine_kernel(const float4* __restrict__ p0, const float4* __restrict__ p1,
                               u16x4* __restrict__ out) {
  int i = blockIdx.x * 256 + threadIdx.x;  // 8192 blocks -> 2M float4
  float4 a = p0[i], b = p1[i];
  u16x4 o;
  o[0] = f2bf(a.x + b.x); o[1] = f2bf(a.y + b.y);
  o[2] = f2bf(a.z + b.z); o[3] = f2bf(a.w + b.w);
  out[i] = o;
}

// ---------------- fused bias + row softmax, bf16 in place ----------------

__global__ __launch_bounds__(256) void softmax_bias_bf16_kernel(
    u16* __restrict__ S, const float2* __restrict__ cq, const float2* __restrict__ cr,
    const float* __restrict__ bwp, int qr0) {
  __shared__ float red[256];
  const int t = threadIdx.x;
  u16* row = S + (size_t)blockIdx.x * NK;
  const float2 cqv = cq[qr0 + blockIdx.x];
  const float bw = bwp[0];

  float l[32];
  float mx = -1e30f;
#pragma unroll
  for (int i = 0; i < 4; ++i) {
    int base = (i * 256 + t) * 8;
    u16x8 u = *(const u16x8*)&row[base];
#pragma unroll
    for (int j = 0; j < 8; ++j) {
      float x = bf2f(u[j]);
      float2 c = cr[base + j];
      float dx = cqv.x - c.x, dy = cqv.y - c.y;
      float lv = x - bw * sqrtf(dx * dx + dy * dy + 1e-8f);
      l[i * 8 + j] = lv;
      mx = fmaxf(mx, lv);
    }
  }
  red[t] = mx; __syncthreads();
  for (int s = 128; s > 0; s >>= 1) { if (t < s) red[t] = fmaxf(red[t], red[t + s]); __syncthreads(); }
  mx = red[0]; __syncthreads();

  float sum = 0.f;
#pragma unroll
  for (int i = 0; i < 32; ++i) { float e = __expf(l[i] - mx); l[i] = e; sum += e; }
  red[t] = sum; __syncthreads();
  for (int s = 128; s > 0; s >>= 1) { if (t < s) red[t] += red[t + s]; __syncthreads(); }
  float inv = 1.f / red[0];

#pragma unroll
  for (int i = 0; i < 4; ++i) {
    int base = (i * 256 + t) * 8;
    u16x8 o;
#pragma unroll
    for (int j = 0; j < 8; ++j) o[j] = f2bf(l[i * 8 + j] * inv);
    *(u16x8*)&row[base] = o;
  }
}

// ---------------- host ----------------

extern "C" void kernel_launch(void* const* d_in, const int* in_sizes, int n_in,
                              void* d_out, int out_size, void* d_ws, size_t ws_size,
                              hipStream_t stream) {
  const float* q  = (const float*)d_in[0];
  const float* k  = (const float*)d_in[1];
  const float* v  = (const float*)d_in[2];
  const float* rb = (const float*)d_in[3];
  const float* qb = (const float*)d_in[4];
  const float* Wq = (const float*)d_in[5];
  const float* Wk = (const float*)d_in[6];
  const float* Wv = (const float*)d_in[7];
  const float* Wp = (const float*)d_in[8];
  const float* bp = (const float*)d_in[9];
  const float* W1 = (const float*)d_in[10];
  const float* b1 = (const float*)d_in[11];
  const float* W2 = (const float*)d_in[12];
  const float* b2 = (const float*)d_in[13];
  float* out = (float*)d_out;

  // qbf|kbf|vbf|qh form a 64 MB contiguous region, all dead by PV time ->
  // reused as the two 32 MB f32 split-K partials.
  char* p = (char*)d_ws;
  const size_t PROJB = (size_t)NQ * DIM * sizeof(u16);  // 16 MB
  u16* qbf = (u16*)p;            p += PROJB;
  u16* kbf = (u16*)p;            p += PROJB;
  u16* vbf = (u16*)p;            p += PROJB;
  u16* qh  = (u16*)p;            p += PROJB;
  u16* kh  = (u16*)p;            p += PROJB;
  u16* vhT = (u16*)p;            p += PROJB;
  u16* WqT = (u16*)p;            p += (size_t)DIM * DIM * 2;
  u16* WkT = (u16*)p;            p += (size_t)DIM * DIM * 2;
  u16* WvT = (u16*)p;            p += (size_t)DIM * DIM * 2;
  u16* WpT = (u16*)p;            p += (size_t)DIM * DIM * 2;
  float* cq  = (float*)p;        p += 2 * NQ * 4;
  float* cr  = (float*)p;        p += 2 * NK * 4;
  float* ps  = (float*)p;        p += 32 * DIM * 4;
  float* pq  = (float*)p;        p += 32 * DIM * 4;
  float* gfv = (float*)p;        p += DIM * 4;
  float* h1p = (float*)p;        p += 8 * 2048 * 4;
  float* bw  = (float*)p;        p += 64;
  size_t fixed_b = (size_t)(p - (char*)d_ws);

  int SR = 256;
  for (int cand = 8192; cand >= 256; cand >>= 1) {
    if (fixed_b + (size_t)cand * (NK + DIM) * 2 <= ws_size) { SR = cand; break; }
  }
  u16* Sbuf = (u16*)p;
  u16* Obuf = Sbuf + (size_t)SR * NK;

  // bias_weight = sigmoid(MLP(var(k, dim=0)))  [f32, tiny]
  var_partial_kernel<<<dim3(4, 32), 256, 0, stream>>>(k, ps, pq);
  gfv_kernel<<<4, 256, 0, stream>>>(ps, pq, gfv);
  h1_partial_kernel<<<dim3(8, 8), 256, 0, stream>>>(gfv, W1, h1p);
  bw_kernel<<<1, 256, 0, stream>>>(h1p, b1, W2, b2, bw);
  centers_kernel<<<32, 256, 0, stream>>>((const float4*)qb, (const float4*)rb,
                                         (float2*)cq, (float2*)cr);

  // convert inputs + weights to bf16 (weights transposed to [N][K])
  const int N4 = NQ * DIM / 4;
  f2bf_vec_kernel<<<2048, 256, 0, stream>>>((const float4*)q, (u16x4*)qbf, N4);
  f2bf_vec_kernel<<<2048, 256, 0, stream>>>((const float4*)k, (u16x4*)kbf, N4);
  f2bf_vec_kernel<<<2048, 256, 0, stream>>>((const float4*)v, (u16x4*)vbf, N4);
  wtrans_kernel<<<dim3(16, 16), 256, 0, stream>>>(Wq, WqT);
  wtrans_kernel<<<dim3(16, 16), 256, 0, stream>>>(Wk, WkT);
  wtrans_kernel<<<dim3(16, 16), 256, 0, stream>>>(Wv, WvT);
  wtrans_kernel<<<dim3(16, 16), 256, 0, stream>>>(Wp, WpT);

  // projections (128^2 kernel): qh = (q@Wq)*hd^-0.5, kh = k@Wk, vhT = (v@Wv)^T
  bgemm_kernel<1><<<dim3(DIM / TN, NQ / TM), 256, 0, stream>>>(
      qbf, WqT, qh, nullptr, NQ, DIM, DIM, DIM, 0.03125f);
  bgemm_kernel<1><<<dim3(DIM / TN, NK / TM), 256, 0, stream>>>(
      kbf, WkT, kh, nullptr, NK, DIM, DIM, DIM, 1.f);
  bgemm_kernel<2><<<dim3(DIM / TN, NK / TM), 256, 0, stream>>>(
      vbf, WvT, vhT, nullptr, NK, DIM, DIM, NK, 1.f);

  if (SR == 8192) {
    // ---- 256^2 pipelined path ----
    // S = qh @ kh^T : M=N=8192, K=1024, grid 32x32, NT=16
    gemm256_kernel<0><<<dim3(1024, 1), 512, 0, stream>>>(
        qh, kh, Sbuf, 16, 32, 4, 2048, 2048, NK, 0, 0, 1.f);
    softmax_bias_bf16_kernel<<<8192, 256, 0, stream>>>(
        Sbuf, (const float2*)cq, (const float2*)cr, bw, 0);
    // O = P @ vh, split-K=2 in one launch, f32 partials into dead qbf..qh
    float* pv0 = (float*)qbf;
    gemm256_kernel<1><<<dim3(128, 2), 512, 0, stream>>>(
        Sbuf, vhT, pv0, 64, 4, 4, 16384, 16384, DIM, 8192, (size_t)8192 * 1024, 1.f);
    combine_kernel<<<8192, 256, 0, stream>>>(
        (const float4*)pv0, (const float4*)(pv0 + (size_t)8192 * 1024), (u16x4*)Obuf);
    // out = O @ Wp + bp
    bgemm_kernel<0><<<dim3(DIM / TN, NQ / TM), 256, 0, stream>>>(
        Obuf, WpT, out, bp, NQ, DIM, DIM, DIM, 1.f);
  } else {
    // ---- fallback: striped path ----
    for (int s0 = 0; s0 < NQ; s0 += SR) {
      bgemm_kernel<1><<<dim3(NK / TN, SR / TM), 256, 0, stream>>>(
          qh + (size_t)s0 * DIM, kh, Sbuf, nullptr, SR, NK, DIM, NK, 1.f);
      softmax_bias_bf16_kernel<<<SR, 256, 0, stream>>>(
          Sbuf, (const float2*)cq, (const float2*)cr, bw, s0);
      bgemm_kernel<1><<<dim3(DIM / TN, SR / TM), 256, 0, stream>>>(
          Sbuf, vhT, Obuf, nullptr, SR, DIM, NK, DIM, 1.f);
      bgemm_kernel<0><<<dim3(DIM / TN, SR / TM), 256, 0, stream>>>(
          Obuf, WpT, out + (size_t)s0 * DIM, bp, SR, DIM, DIM, DIM, 1.f);
    }
  }
}